// Round 2
// baseline (697.561 us; speedup 1.0000x reference)
//
#include <hip/hip_runtime.h>
#include <math.h>

#define NEG_SLOPE 0.2f

__device__ __forceinline__ float wave_reduce_sum(float v){
  #pragma unroll
  for (int off = 32; off > 0; off >>= 1) v += __shfl_xor(v, off, 64);
  return v;
}
__device__ __forceinline__ float wave_reduce_max(float v){
  #pragma unroll
  for (int off = 32; off > 0; off >>= 1) v = fmaxf(v, __shfl_xor(v, off, 64));
  return v;
}

// ---------------- CSR build ----------------

__global__ void k_hist(const int* __restrict__ ei, int* __restrict__ deg, int E, int N){
  int e = blockIdx.x * blockDim.x + threadIdx.x;
  if (e >= E + N) return;
  int d = (e < E) ? ei[E + e] : (e - E);   // self loops appended after edges
  atomicAdd(&deg[d], 1);
}

// block of 256 threads scans 1024 elements (4/thread)
__global__ void k_scan_a(const int* __restrict__ deg, int* __restrict__ rowptr,
                         int* __restrict__ bsums, int n){
  __shared__ int lds[256];
  int t = threadIdx.x;
  int base = blockIdx.x * 1024 + t * 4;
  int v[4]; int s = 0;
  #pragma unroll
  for (int i = 0; i < 4; i++){ int idx = base + i; v[i] = (idx < n) ? deg[idx] : 0; s += v[i]; }
  lds[t] = s; __syncthreads();
  for (int off = 1; off < 256; off <<= 1){
    int x = (t >= off) ? lds[t - off] : 0;
    __syncthreads();
    lds[t] += x;
    __syncthreads();
  }
  int excl = lds[t] - s;
  if (t == 255) bsums[blockIdx.x] = lds[255];
  int run = excl;
  #pragma unroll
  for (int i = 0; i < 4; i++){ int idx = base + i; if (idx < n) rowptr[idx] = run; run += v[i]; }
}

__global__ void k_scan_b(int* __restrict__ bsums, int nb){
  __shared__ int lds[128];
  int t = threadIdx.x;
  int v = (t < nb) ? bsums[t] : 0;
  lds[t] = v; __syncthreads();
  for (int off = 1; off < 128; off <<= 1){
    int x = (t >= off) ? lds[t - off] : 0;
    __syncthreads();
    lds[t] += x;
    __syncthreads();
  }
  if (t < nb) bsums[t] = lds[t] - v;
}

__global__ void k_scan_c(int* __restrict__ rowptr, const int* __restrict__ bsums,
                         int* __restrict__ cursor, int n, int total){
  int i = blockIdx.x * blockDim.x + threadIdx.x;
  if (i < n){
    int v = rowptr[i] + bsums[i >> 10];
    rowptr[i] = v;
    cursor[i] = v;
  } else if (i == n){
    rowptr[n] = total;
  }
}

__global__ void k_scatter(const int* __restrict__ ei, int* __restrict__ cursor,
                          int* __restrict__ col, int E, int N){
  int e = blockIdx.x * blockDim.x + threadIdx.x;
  if (e >= E + N) return;
  int s, d;
  if (e < E){ s = ei[e]; d = ei[E + e]; } else { s = e - E; d = s; }
  int pos = atomicAdd(&cursor[d], 1);
  col[pos] = s;
}

// ---------------- dense ops ----------------

// h[n][c] = sum_k x[n][k] * W[k][c]  (K=16, C=64); also s[n]=h.a_src, d[n]=h.a_dst
__global__ void k_dense16(const float* __restrict__ x, const float* __restrict__ W,
                          const float* __restrict__ asrc, const float* __restrict__ adst,
                          float* __restrict__ h, float* __restrict__ sarr, float* __restrict__ darr,
                          int n){
  __shared__ float Ws[16 * 64];
  int t = threadIdx.x;
  for (int i = t; i < 16 * 64; i += blockDim.x) Ws[i] = W[i];
  __syncthreads();
  int node = blockIdx.x * (blockDim.x >> 6) + (t >> 6);
  if (node >= n) return;
  int lane = t & 63;
  const float* xr = x + (size_t)node * 16;
  float acc = 0.f;
  #pragma unroll
  for (int k = 0; k < 16; k++) acc = fmaf(xr[k], Ws[k * 64 + lane], acc);
  h[(size_t)node * 64 + lane] = acc;
  float sv = wave_reduce_sum(acc * asrc[lane]);
  float dv = wave_reduce_sum(acc * adst[lane]);
  if (lane == 0){ sarr[node] = sv; darr[node] = dv; }
}

// h[n][c] = sum_k x[n][k] * W[k][c]  (K=64, C=64); also s,d
__global__ void k_dense64(const float* __restrict__ x, const float* __restrict__ W,
                          const float* __restrict__ asrc, const float* __restrict__ adst,
                          float* __restrict__ h, float* __restrict__ sarr, float* __restrict__ darr,
                          int n){
  __shared__ float Ws[64 * 64];
  int t = threadIdx.x;
  for (int i = t; i < 64 * 64; i += blockDim.x) Ws[i] = W[i];
  __syncthreads();
  int node = blockIdx.x * (blockDim.x >> 6) + (t >> 6);
  if (node >= n) return;
  int lane = t & 63;
  const float* xr = x + (size_t)node * 64;
  float acc = 0.f;
  #pragma unroll
  for (int k = 0; k < 64; k++) acc = fmaf(xr[k], Ws[k * 64 + lane], acc);
  h[(size_t)node * 64 + lane] = acc;
  float sv = wave_reduce_sum(acc * asrc[lane]);
  float dv = wave_reduce_sum(acc * adst[lane]);
  if (lane == 0){ sarr[node] = sv; darr[node] = dv; }
}

// ---------------- GAT softmax-aggregate (wave per node) ----------------

__global__ void k_agg(const float* __restrict__ h, const float* __restrict__ sarr,
                      const float* __restrict__ darr, const int* __restrict__ rowptr,
                      const int* __restrict__ col, const float* __restrict__ bias,
                      float* __restrict__ out, int n){
  int node = blockIdx.x * (blockDim.x >> 6) + (threadIdx.x >> 6);
  if (node >= n) return;
  int lane = threadIdx.x & 63;
  int beg = rowptr[node], end = rowptr[node + 1];
  float dn = darr[node];

  // pass 1: segment max (lanes strided over edges)
  float m = -INFINITY;
  for (int j = beg + lane; j < end; j += 64){
    float e = sarr[col[j]] + dn;
    e = (e > 0.f) ? e : NEG_SLOPE * e;
    m = fmaxf(m, e);
  }
  m = wave_reduce_max(m);

  // pass 2: denominator
  float sum = 0.f;
  for (int j = beg + lane; j < end; j += 64){
    float e = sarr[col[j]] + dn;
    e = (e > 0.f) ? e : NEG_SLOPE * e;
    sum += expf(e - m);
  }
  sum = wave_reduce_sum(sum);
  float invden = 1.0f / (sum + 1e-16f);

  // pass 3: weighted aggregation, lane = channel
  float acc = 0.f;
  for (int j = beg; j < end; j++){
    int s = col[j];
    float e = sarr[s] + dn;
    e = (e > 0.f) ? e : NEG_SLOPE * e;
    float alpha = expf(e - m) * invden;
    acc = fmaf(alpha, h[(size_t)s * 64 + lane], acc);
  }
  float r = acc + bias[lane];
  out[(size_t)node * 64 + lane] = fmaxf(r, 0.f);   // relu (both layers)
}

// ---------------- policy head ----------------

__global__ void k_policy(const float* __restrict__ x, const float* __restrict__ Wp,
                         const float* __restrict__ bp, float* __restrict__ out, int n){
  __shared__ float Ws[64 * 8];
  __shared__ float bs[8];
  int t = threadIdx.x;
  for (int i = t; i < 64 * 8; i += blockDim.x) Ws[i] = Wp[i];
  if (t < 8) bs[t] = bp[t];
  __syncthreads();
  int idx = blockIdx.x * blockDim.x + t;
  if (idx >= n * 8) return;
  int node = idx >> 3, o = idx & 7;
  const float* xr = x + (size_t)node * 64;
  float acc = bs[o];
  #pragma unroll
  for (int k = 0; k < 64; k++) acc = fmaf(xr[k], Ws[k * 8 + o], acc);
  out[idx] = acc;
}

// ---------------- launch ----------------

extern "C" void kernel_launch(void* const* d_in, const int* in_sizes, int n_in,
                              void* d_out, int out_size, void* d_ws, size_t ws_size,
                              hipStream_t stream) {
  const float* x   = (const float*)d_in[0];
  const int*   ei  = (const int*)  d_in[1];
  const float* W1  = (const float*)d_in[2];
  const float* as1 = (const float*)d_in[3];
  const float* ad1 = (const float*)d_in[4];
  const float* b1  = (const float*)d_in[5];
  const float* W2  = (const float*)d_in[6];
  const float* as2 = (const float*)d_in[7];
  const float* ad2 = (const float*)d_in[8];
  const float* b2  = (const float*)d_in[9];
  const float* Wp  = (const float*)d_in[10];
  const float* bp  = (const float*)d_in[11];
  float* out = (float*)d_out;

  int N = in_sizes[0] / 16;
  int E = in_sizes[1] / 2;
  int TOT = E + N;

  char* p = (char*)d_ws;
  auto alloc = [&](size_t bytes) -> char* {
    char* r = p; p += (bytes + 255) & ~(size_t)255; return r;
  };
  float* h      = (float*)alloc((size_t)N * 64 * 4);
  float* buf    = (float*)alloc((size_t)N * 64 * 4);
  float* sA     = (float*)alloc((size_t)N * 4);
  float* dA     = (float*)alloc((size_t)N * 4);
  int*   deg    = (int*)  alloc((size_t)N * 4);
  int*   rowptr = (int*)  alloc((size_t)(N + 1) * 4);
  int*   cursor = (int*)  alloc((size_t)N * 4);
  int*   col    = (int*)  alloc((size_t)TOT * 4);
  int*   bsums  = (int*)  alloc(128 * 4);

  const int tb = 256;

  // CSR build (dst-grouped)
  (void)hipMemsetAsync(deg, 0, (size_t)N * 4, stream);
  k_hist<<<(TOT + tb - 1) / tb, tb, 0, stream>>>(ei, deg, E, N);
  int nb = (N + 1023) / 1024;
  k_scan_a<<<nb, 256, 0, stream>>>(deg, rowptr, bsums, N);
  k_scan_b<<<1, 128, 0, stream>>>(bsums, nb);
  k_scan_c<<<(N + 1 + tb - 1) / tb, tb, 0, stream>>>(rowptr, bsums, cursor, N, TOT);
  k_scatter<<<(TOT + tb - 1) / tb, tb, 0, stream>>>(ei, cursor, col, E, N);

  // layer 1
  k_dense16<<<(N + 3) / 4, 256, 0, stream>>>(x, W1, as1, ad1, h, sA, dA, N);
  k_agg<<<(N + 3) / 4, 256, 0, stream>>>(h, sA, dA, rowptr, col, b1, buf, N);
  // layer 2
  k_dense64<<<(N + 3) / 4, 256, 0, stream>>>(buf, W2, as2, ad2, h, sA, dA, N);
  k_agg<<<(N + 3) / 4, 256, 0, stream>>>(h, sA, dA, rowptr, col, b2, buf, N);
  // policy head
  k_policy<<<((size_t)N * 8 + tb - 1) / tb, tb, 0, stream>>>(buf, Wp, bp, out, N);
}

// Round 3
// 481.062 us; speedup vs baseline: 1.4500x; 1.4500x over previous
//
#include <hip/hip_runtime.h>
#include <math.h>

#define NEG_SLOPE 0.2f

__device__ __forceinline__ float wave_reduce_sum(float v){
  #pragma unroll
  for (int off = 32; off > 0; off >>= 1) v += __shfl_xor(v, off, 64);
  return v;
}
__device__ __forceinline__ float wave_reduce_max(float v){
  #pragma unroll
  for (int off = 32; off > 0; off >>= 1) v = fmaxf(v, __shfl_xor(v, off, 64));
  return v;
}

// ---------------- CSR build ----------------

__global__ void k_hist(const int* __restrict__ ei, int* __restrict__ deg, int E, int N){
  int e = blockIdx.x * blockDim.x + threadIdx.x;
  if (e >= E + N) return;
  int d = (e < E) ? ei[E + e] : (e - E);   // self loops appended after edges
  atomicAdd(&deg[d], 1);
}

// block of 256 threads scans 1024 elements (4/thread)
__global__ void k_scan_a(const int* __restrict__ deg, int* __restrict__ rowptr,
                         int* __restrict__ bsums, int n){
  __shared__ int lds[256];
  int t = threadIdx.x;
  int base = blockIdx.x * 1024 + t * 4;
  int v[4]; int s = 0;
  #pragma unroll
  for (int i = 0; i < 4; i++){ int idx = base + i; v[i] = (idx < n) ? deg[idx] : 0; s += v[i]; }
  lds[t] = s; __syncthreads();
  for (int off = 1; off < 256; off <<= 1){
    int x = (t >= off) ? lds[t - off] : 0;
    __syncthreads();
    lds[t] += x;
    __syncthreads();
  }
  int excl = lds[t] - s;
  if (t == 255) bsums[blockIdx.x] = lds[255];
  int run = excl;
  #pragma unroll
  for (int i = 0; i < 4; i++){ int idx = base + i; if (idx < n) rowptr[idx] = run; run += v[i]; }
}

__global__ void k_scan_b(int* __restrict__ bsums, int nb){
  __shared__ int lds[128];
  int t = threadIdx.x;
  int v = (t < nb) ? bsums[t] : 0;
  lds[t] = v; __syncthreads();
  for (int off = 1; off < 128; off <<= 1){
    int x = (t >= off) ? lds[t - off] : 0;
    __syncthreads();
    lds[t] += x;
    __syncthreads();
  }
  if (t < nb) bsums[t] = lds[t] - v;
}

__global__ void k_scan_c(int* __restrict__ rowptr, const int* __restrict__ bsums,
                         int* __restrict__ cursor, int n, int total){
  int i = blockIdx.x * blockDim.x + threadIdx.x;
  if (i < n){
    int v = rowptr[i] + bsums[i >> 10];
    rowptr[i] = v;
    cursor[i] = v;
  } else if (i == n){
    rowptr[n] = total;
  }
}

__global__ void k_scatter(const int* __restrict__ ei, int* __restrict__ cursor,
                          int* __restrict__ col, int E, int N){
  int e = blockIdx.x * blockDim.x + threadIdx.x;
  if (e >= E + N) return;
  int s, d;
  if (e < E){ s = ei[e]; d = ei[E + e]; } else { s = e - E; d = s; }
  int pos = atomicAdd(&cursor[d], 1);
  col[pos] = s;
}

// ---------------- dense ops ----------------

__global__ void k_dense16(const float* __restrict__ x, const float* __restrict__ W,
                          const float* __restrict__ asrc, const float* __restrict__ adst,
                          float* __restrict__ h, float* __restrict__ sarr, float* __restrict__ darr,
                          int n){
  __shared__ float Ws[16 * 64];
  int t = threadIdx.x;
  for (int i = t; i < 16 * 64; i += blockDim.x) Ws[i] = W[i];
  __syncthreads();
  int node = blockIdx.x * (blockDim.x >> 6) + (t >> 6);
  if (node >= n) return;
  int lane = t & 63;
  const float* xr = x + (size_t)node * 16;
  float acc = 0.f;
  #pragma unroll
  for (int k = 0; k < 16; k++) acc = fmaf(xr[k], Ws[k * 64 + lane], acc);
  h[(size_t)node * 64 + lane] = acc;
  float sv = wave_reduce_sum(acc * asrc[lane]);
  float dv = wave_reduce_sum(acc * adst[lane]);
  if (lane == 0){ sarr[node] = sv; darr[node] = dv; }
}

__global__ void k_dense64(const float* __restrict__ x, const float* __restrict__ W,
                          const float* __restrict__ asrc, const float* __restrict__ adst,
                          float* __restrict__ h, float* __restrict__ sarr, float* __restrict__ darr,
                          int n){
  __shared__ float Ws[64 * 64];
  int t = threadIdx.x;
  for (int i = t; i < 64 * 64; i += blockDim.x) Ws[i] = W[i];
  __syncthreads();
  int node = blockIdx.x * (blockDim.x >> 6) + (t >> 6);
  if (node >= n) return;
  int lane = t & 63;
  const float* xr = x + (size_t)node * 64;
  float acc = 0.f;
  #pragma unroll
  for (int k = 0; k < 64; k++) acc = fmaf(xr[k], Ws[k * 64 + lane], acc);
  h[(size_t)node * 64 + lane] = acc;
  float sv = wave_reduce_sum(acc * asrc[lane]);
  float dv = wave_reduce_sum(acc * adst[lane]);
  if (lane == 0){ sarr[node] = sv; darr[node] = dv; }
}

// ---------------- GAT softmax-aggregate (wave per node) ----------------

__global__ void k_agg(const float* __restrict__ h, const float* __restrict__ sarr,
                      const float* __restrict__ darr, const int* __restrict__ rowptr,
                      const int* __restrict__ col, const float* __restrict__ bias,
                      float* __restrict__ out, int n){
  int node = blockIdx.x * (blockDim.x >> 6) + (threadIdx.x >> 6);
  if (node >= n) return;
  int lane = threadIdx.x & 63;
  int beg = rowptr[node], end = rowptr[node + 1];
  int deg = end - beg;
  float dn = darr[node];

  if (deg <= 128){
    // --- cached fast path: edge data lives in 2 regs/lane ---
    int c0 = 0, c1 = 0;
    float e0 = -INFINITY, e1 = -INFINITY;
    if (lane < deg){
      c0 = col[beg + lane];
      float t = sarr[c0] + dn;
      e0 = (t > 0.f) ? t : NEG_SLOPE * t;
    }
    if (lane + 64 < deg){
      c1 = col[beg + lane + 64];
      float t = sarr[c1] + dn;
      e1 = (t > 0.f) ? t : NEG_SLOPE * t;
    }
    float m = wave_reduce_max(fmaxf(e0, e1));
    float w0 = (lane < deg)      ? __expf(e0 - m) : 0.f;
    float w1 = (lane + 64 < deg) ? __expf(e1 - m) : 0.f;
    float sum = wave_reduce_sum(w0 + w1);
    float inv = 1.f / (sum + 1e-16f);
    float a0 = w0 * inv, a1 = w1 * inv;

    // pass 3: 4 edge-groups x 16 channel-quads; 4 h-rows in flight
    int eg = lane >> 4, cq = lane & 15;
    float4 acc = make_float4(0.f, 0.f, 0.f, 0.f);
    for (int j0 = 0; j0 < deg; j0 += 4){
      int idx = j0 + eg;
      int sl = idx & 63;
      int   sA = __shfl(c0, sl);
      int   sB = __shfl(c1, sl);
      float aA = __shfl(a0, sl);
      float aB = __shfl(a1, sl);
      int   s  = (idx & 64) ? sB : sA;
      float a  = (idx & 64) ? aB : aA;
      if (idx < deg){
        const float4 hv = *(const float4*)(h + (size_t)s * 64 + cq * 4);
        acc.x = fmaf(a, hv.x, acc.x);
        acc.y = fmaf(a, hv.y, acc.y);
        acc.z = fmaf(a, hv.z, acc.z);
        acc.w = fmaf(a, hv.w, acc.w);
      }
    }
    // reduce across the 4 edge-groups
    acc.x += __shfl_xor(acc.x, 16); acc.x += __shfl_xor(acc.x, 32);
    acc.y += __shfl_xor(acc.y, 16); acc.y += __shfl_xor(acc.y, 32);
    acc.z += __shfl_xor(acc.z, 16); acc.z += __shfl_xor(acc.z, 32);
    acc.w += __shfl_xor(acc.w, 16); acc.w += __shfl_xor(acc.w, 32);
    if (eg == 0){
      const float4 bv = *(const float4*)(bias + cq * 4);
      float4 r;
      r.x = fmaxf(acc.x + bv.x, 0.f);
      r.y = fmaxf(acc.y + bv.y, 0.f);
      r.z = fmaxf(acc.z + bv.z, 0.f);
      r.w = fmaxf(acc.w + bv.w, 0.f);
      *(float4*)(out + (size_t)node * 64 + cq * 4) = r;
    }
  } else {
    // --- generic fallback (3-pass, recompute) ---
    float m = -INFINITY;
    for (int j = beg + lane; j < end; j += 64){
      float e = sarr[col[j]] + dn;
      e = (e > 0.f) ? e : NEG_SLOPE * e;
      m = fmaxf(m, e);
    }
    m = wave_reduce_max(m);
    float sum = 0.f;
    for (int j = beg + lane; j < end; j += 64){
      float e = sarr[col[j]] + dn;
      e = (e > 0.f) ? e : NEG_SLOPE * e;
      sum += __expf(e - m);
    }
    sum = wave_reduce_sum(sum);
    float invden = 1.0f / (sum + 1e-16f);
    float acc = 0.f;
    for (int j = beg; j < end; j++){
      int s = col[j];
      float e = sarr[s] + dn;
      e = (e > 0.f) ? e : NEG_SLOPE * e;
      float alpha = __expf(e - m) * invden;
      acc = fmaf(alpha, h[(size_t)s * 64 + lane], acc);
    }
    float r = acc + bias[lane];
    out[(size_t)node * 64 + lane] = fmaxf(r, 0.f);
  }
}

// ---------------- policy head ----------------

__global__ void k_policy(const float* __restrict__ x, const float* __restrict__ Wp,
                         const float* __restrict__ bp, float* __restrict__ out, int n){
  __shared__ float Ws[64 * 8];
  __shared__ float bs[8];
  int t = threadIdx.x;
  for (int i = t; i < 64 * 8; i += blockDim.x) Ws[i] = Wp[i];
  if (t < 8) bs[t] = bp[t];
  __syncthreads();
  int idx = blockIdx.x * blockDim.x + t;
  if (idx >= n * 8) return;
  int node = idx >> 3, o = idx & 7;
  const float* xr = x + (size_t)node * 64;
  float acc = bs[o];
  #pragma unroll
  for (int k = 0; k < 64; k++) acc = fmaf(xr[k], Ws[k * 8 + o], acc);
  out[idx] = acc;
}

// ---------------- launch ----------------

extern "C" void kernel_launch(void* const* d_in, const int* in_sizes, int n_in,
                              void* d_out, int out_size, void* d_ws, size_t ws_size,
                              hipStream_t stream) {
  const float* x   = (const float*)d_in[0];
  const int*   ei  = (const int*)  d_in[1];
  const float* W1  = (const float*)d_in[2];
  const float* as1 = (const float*)d_in[3];
  const float* ad1 = (const float*)d_in[4];
  const float* b1  = (const float*)d_in[5];
  const float* W2  = (const float*)d_in[6];
  const float* as2 = (const float*)d_in[7];
  const float* ad2 = (const float*)d_in[8];
  const float* b2  = (const float*)d_in[9];
  const float* Wp  = (const float*)d_in[10];
  const float* bp  = (const float*)d_in[11];
  float* out = (float*)d_out;

  int N = in_sizes[0] / 16;
  int E = in_sizes[1] / 2;
  int TOT = E + N;

  char* p = (char*)d_ws;
  auto alloc = [&](size_t bytes) -> char* {
    char* r = p; p += (bytes + 255) & ~(size_t)255; return r;
  };
  float* h      = (float*)alloc((size_t)N * 64 * 4);
  float* buf    = (float*)alloc((size_t)N * 64 * 4);
  float* sA     = (float*)alloc((size_t)N * 4);
  float* dA     = (float*)alloc((size_t)N * 4);
  int*   deg    = (int*)  alloc((size_t)N * 4);
  int*   rowptr = (int*)  alloc((size_t)(N + 1) * 4);
  int*   cursor = (int*)  alloc((size_t)N * 4);
  int*   col    = (int*)  alloc((size_t)TOT * 4);
  int*   bsums  = (int*)  alloc(128 * 4);

  const int tb = 256;

  // CSR build (dst-grouped)
  (void)hipMemsetAsync(deg, 0, (size_t)N * 4, stream);
  k_hist<<<(TOT + tb - 1) / tb, tb, 0, stream>>>(ei, deg, E, N);
  int nb = (N + 1023) / 1024;
  k_scan_a<<<nb, 256, 0, stream>>>(deg, rowptr, bsums, N);
  k_scan_b<<<1, 128, 0, stream>>>(bsums, nb);
  k_scan_c<<<(N + 1 + tb - 1) / tb, tb, 0, stream>>>(rowptr, bsums, cursor, N, TOT);
  k_scatter<<<(TOT + tb - 1) / tb, tb, 0, stream>>>(ei, cursor, col, E, N);

  // layer 1
  k_dense16<<<(N + 3) / 4, 256, 0, stream>>>(x, W1, as1, ad1, h, sA, dA, N);
  k_agg<<<(N + 3) / 4, 256, 0, stream>>>(h, sA, dA, rowptr, col, b1, buf, N);
  // layer 2
  k_dense64<<<(N + 3) / 4, 256, 0, stream>>>(buf, W2, as2, ad2, h, sA, dA, N);
  k_agg<<<(N + 3) / 4, 256, 0, stream>>>(h, sA, dA, rowptr, col, b2, buf, N);
  // policy head
  k_policy<<<((size_t)N * 8 + tb - 1) / tb, tb, 0, stream>>>(buf, Wp, bp, out, N);
}

// Round 4
// 394.859 us; speedup vs baseline: 1.7666x; 1.2183x over previous
//
#include <hip/hip_runtime.h>
#include <math.h>

#define NEG_SLOPE 0.2f
#define TILE 8192

__device__ __forceinline__ float wave_reduce_sum(float v){
  #pragma unroll
  for (int off = 32; off > 0; off >>= 1) v += __shfl_xor(v, off, 64);
  return v;
}
__device__ __forceinline__ float wave_reduce_max(float v){
  #pragma unroll
  for (int off = 32; off > 0; off >>= 1) v = fmaxf(v, __shfl_xor(v, off, 64));
  return v;
}

// ---------------- CSR build ----------------

__global__ void k_hist(const int* __restrict__ ei, int* __restrict__ deg, int E, int N){
  int e = blockIdx.x * blockDim.x + threadIdx.x;
  if (e >= E + N) return;
  int d = (e < E) ? ei[E + e] : (e - E);   // self loops appended after edges
  atomicAdd(&deg[d], 1);
}

// block of 256 threads scans 1024 elements (4/thread)
__global__ void k_scan_a(const int* __restrict__ deg, int* __restrict__ rowptr,
                         int* __restrict__ bsums, int n){
  __shared__ int lds[256];
  int t = threadIdx.x;
  int base = blockIdx.x * 1024 + t * 4;
  int v[4]; int s = 0;
  #pragma unroll
  for (int i = 0; i < 4; i++){ int idx = base + i; v[i] = (idx < n) ? deg[idx] : 0; s += v[i]; }
  lds[t] = s; __syncthreads();
  for (int off = 1; off < 256; off <<= 1){
    int x = (t >= off) ? lds[t - off] : 0;
    __syncthreads();
    lds[t] += x;
    __syncthreads();
  }
  int excl = lds[t] - s;
  if (t == 255) bsums[blockIdx.x] = lds[255];
  int run = excl;
  #pragma unroll
  for (int i = 0; i < 4; i++){ int idx = base + i; if (idx < n) rowptr[idx] = run; run += v[i]; }
}

__global__ void k_scan_b(int* __restrict__ bsums, int nb){
  __shared__ int lds[128];
  int t = threadIdx.x;
  int v = (t < nb) ? bsums[t] : 0;
  lds[t] = v; __syncthreads();
  for (int off = 1; off < 128; off <<= 1){
    int x = (t >= off) ? lds[t - off] : 0;
    __syncthreads();
    lds[t] += x;
    __syncthreads();
  }
  if (t < nb) bsums[t] = lds[t] - v;
}

__global__ void k_scan_c(int* __restrict__ rowptr, const int* __restrict__ bsums,
                         int n, int total){
  int i = blockIdx.x * blockDim.x + threadIdx.x;
  if (i < n){
    rowptr[i] = rowptr[i] + bsums[i >> 10];
  } else if (i == n){
    rowptr[n] = total;
  }
}

// --- bucketed scatter: bucket = 256 consecutive dst nodes ---

__global__ void k_bcount(const int* __restrict__ ei, int* __restrict__ C,
                         int E, int TOT, int NB, int T){
  __shared__ int hist[512];
  int t = blockIdx.x;
  for (int i = threadIdx.x; i < NB; i += blockDim.x) hist[i] = 0;
  __syncthreads();
  int base = t * TILE;
  for (int k = threadIdx.x; k < TILE; k += blockDim.x){
    int j = base + k;
    if (j < TOT){
      int d = (j < E) ? ei[E + j] : (j - E);
      atomicAdd(&hist[d >> 8], 1);
    }
  }
  __syncthreads();
  for (int b = threadIdx.x; b < NB; b += blockDim.x) C[(size_t)b * T + t] = hist[b];
}

// one wave per bucket: exclusive scan of C[b][*] over tiles, absolute base from rowptr
__global__ void k_bcolscan(const int* __restrict__ C, const int* __restrict__ rowptr,
                           int* __restrict__ O, int NB, int T){
  int wid = (blockIdx.x * blockDim.x + threadIdx.x) >> 6;
  int lane = threadIdx.x & 63;
  if (wid >= NB) return;
  int run = rowptr[wid << 8];
  int nchunks = (T + 63) / 64;
  for (int i = 0; i < nchunks; i++){
    int t = i * 64 + lane;
    int v = (t < T) ? C[(size_t)wid * T + t] : 0;
    int s = v;
    #pragma unroll
    for (int off = 1; off < 64; off <<= 1){
      int u = __shfl_up(s, off);
      if (lane >= off) s += u;
    }
    if (t < T) O[(size_t)wid * T + t] = run + (s - v);
    run += __shfl(s, 63);
  }
}

__global__ void k_bscatter(const int* __restrict__ ei, const int* __restrict__ O,
                           unsigned int* __restrict__ tmp, int E, int TOT, int NB, int T){
  __shared__ int cur[512];
  int t = blockIdx.x;
  for (int b = threadIdx.x; b < NB; b += blockDim.x) cur[b] = O[(size_t)b * T + t];
  __syncthreads();
  int base = t * TILE;
  for (int k = threadIdx.x; k < TILE; k += blockDim.x){
    int j = base + k;
    if (j < TOT){
      int s, d;
      if (j < E){ s = ei[j]; d = ei[E + j]; } else { s = j - E; d = s; }
      int r = atomicAdd(&cur[d >> 8], 1);
      tmp[r] = ((unsigned)s << 8) | (unsigned)(d & 255);
    }
  }
}

// one block per bucket: scatter within the bucket's private col window
__global__ void k_bfinal(const unsigned int* __restrict__ tmp, const int* __restrict__ rowptr,
                         int* __restrict__ col, int N, int TOT){
  __shared__ int cur[256];
  int b = blockIdx.x;
  int base_node = b << 8;
  int nnode = min(256, N - base_node);
  if ((int)threadIdx.x < nnode) cur[threadIdx.x] = rowptr[base_node + threadIdx.x];
  __syncthreads();
  int beg = rowptr[base_node];
  int end = rowptr[base_node + nnode];
  for (int j = beg + (int)threadIdx.x; j < end; j += blockDim.x){
    unsigned v = tmp[j];
    int pos = atomicAdd(&cur[v & 255u], 1);
    col[pos] = (int)(v >> 8);
  }
}

// ---------------- dense ops ----------------

__global__ void k_dense16(const float* __restrict__ x, const float* __restrict__ W,
                          const float* __restrict__ asrc, const float* __restrict__ adst,
                          float* __restrict__ h, float* __restrict__ sarr, float* __restrict__ darr,
                          int n){
  __shared__ float Ws[16 * 64];
  int t = threadIdx.x;
  for (int i = t; i < 16 * 64; i += blockDim.x) Ws[i] = W[i];
  __syncthreads();
  int node = blockIdx.x * (blockDim.x >> 6) + (t >> 6);
  if (node >= n) return;
  int lane = t & 63;
  const float* xr = x + (size_t)node * 16;
  float acc = 0.f;
  #pragma unroll
  for (int k = 0; k < 16; k++) acc = fmaf(xr[k], Ws[k * 64 + lane], acc);
  h[(size_t)node * 64 + lane] = acc;
  float sv = wave_reduce_sum(acc * asrc[lane]);
  float dv = wave_reduce_sum(acc * adst[lane]);
  if (lane == 0){ sarr[node] = sv; darr[node] = dv; }
}

__global__ void k_dense64(const float* __restrict__ x, const float* __restrict__ W,
                          const float* __restrict__ asrc, const float* __restrict__ adst,
                          float* __restrict__ h, float* __restrict__ sarr, float* __restrict__ darr,
                          int n){
  __shared__ float Ws[64 * 64];
  int t = threadIdx.x;
  for (int i = t; i < 64 * 64; i += blockDim.x) Ws[i] = W[i];
  __syncthreads();
  int node = blockIdx.x * (blockDim.x >> 6) + (t >> 6);
  if (node >= n) return;
  int lane = t & 63;
  const float* xr = x + (size_t)node * 64;
  float acc = 0.f;
  #pragma unroll
  for (int k = 0; k < 64; k++) acc = fmaf(xr[k], Ws[k * 64 + lane], acc);
  h[(size_t)node * 64 + lane] = acc;
  float sv = wave_reduce_sum(acc * asrc[lane]);
  float dv = wave_reduce_sum(acc * adst[lane]);
  if (lane == 0){ sarr[node] = sv; darr[node] = dv; }
}

// ---------------- GAT softmax-aggregate (wave per node) ----------------

__global__ void k_agg(const float* __restrict__ h, const float* __restrict__ sarr,
                      const float* __restrict__ darr, const int* __restrict__ rowptr,
                      const int* __restrict__ col, const float* __restrict__ bias,
                      float* __restrict__ out, int n){
  int node = blockIdx.x * (blockDim.x >> 6) + (threadIdx.x >> 6);
  if (node >= n) return;
  int lane = threadIdx.x & 63;
  int beg = rowptr[node], end = rowptr[node + 1];
  int deg = end - beg;
  float dn = darr[node];

  if (deg <= 128){
    int c0 = 0, c1 = 0;
    float e0 = -INFINITY, e1 = -INFINITY;
    if (lane < deg){
      c0 = col[beg + lane];
      float t = sarr[c0] + dn;
      e0 = (t > 0.f) ? t : NEG_SLOPE * t;
    }
    if (lane + 64 < deg){
      c1 = col[beg + lane + 64];
      float t = sarr[c1] + dn;
      e1 = (t > 0.f) ? t : NEG_SLOPE * t;
    }
    float m = wave_reduce_max(fmaxf(e0, e1));
    float w0 = (lane < deg)      ? __expf(e0 - m) : 0.f;
    float w1 = (lane + 64 < deg) ? __expf(e1 - m) : 0.f;
    float sum = wave_reduce_sum(w0 + w1);
    float inv = 1.f / (sum + 1e-16f);
    float a0 = w0 * inv, a1 = w1 * inv;

    int eg = lane >> 4, cq = lane & 15;
    float4 acc = make_float4(0.f, 0.f, 0.f, 0.f);
    for (int j0 = 0; j0 < deg; j0 += 4){
      int idx = j0 + eg;
      int sl = idx & 63;
      int   sA = __shfl(c0, sl);
      int   sB = __shfl(c1, sl);
      float aA = __shfl(a0, sl);
      float aB = __shfl(a1, sl);
      int   s  = (idx & 64) ? sB : sA;
      float a  = (idx & 64) ? aB : aA;
      if (idx < deg){
        const float4 hv = *(const float4*)(h + (size_t)s * 64 + cq * 4);
        acc.x = fmaf(a, hv.x, acc.x);
        acc.y = fmaf(a, hv.y, acc.y);
        acc.z = fmaf(a, hv.z, acc.z);
        acc.w = fmaf(a, hv.w, acc.w);
      }
    }
    acc.x += __shfl_xor(acc.x, 16); acc.x += __shfl_xor(acc.x, 32);
    acc.y += __shfl_xor(acc.y, 16); acc.y += __shfl_xor(acc.y, 32);
    acc.z += __shfl_xor(acc.z, 16); acc.z += __shfl_xor(acc.z, 32);
    acc.w += __shfl_xor(acc.w, 16); acc.w += __shfl_xor(acc.w, 32);
    if (eg == 0){
      const float4 bv = *(const float4*)(bias + cq * 4);
      float4 r;
      r.x = fmaxf(acc.x + bv.x, 0.f);
      r.y = fmaxf(acc.y + bv.y, 0.f);
      r.z = fmaxf(acc.z + bv.z, 0.f);
      r.w = fmaxf(acc.w + bv.w, 0.f);
      *(float4*)(out + (size_t)node * 64 + cq * 4) = r;
    }
  } else {
    float m = -INFINITY;
    for (int j = beg + lane; j < end; j += 64){
      float e = sarr[col[j]] + dn;
      e = (e > 0.f) ? e : NEG_SLOPE * e;
      m = fmaxf(m, e);
    }
    m = wave_reduce_max(m);
    float sum = 0.f;
    for (int j = beg + lane; j < end; j += 64){
      float e = sarr[col[j]] + dn;
      e = (e > 0.f) ? e : NEG_SLOPE * e;
      sum += __expf(e - m);
    }
    sum = wave_reduce_sum(sum);
    float invden = 1.0f / (sum + 1e-16f);
    float acc = 0.f;
    for (int j = beg; j < end; j++){
      int s = col[j];
      float e = sarr[s] + dn;
      e = (e > 0.f) ? e : NEG_SLOPE * e;
      float alpha = __expf(e - m) * invden;
      acc = fmaf(alpha, h[(size_t)s * 64 + lane], acc);
    }
    float r = acc + bias[lane];
    out[(size_t)node * 64 + lane] = fmaxf(r, 0.f);
  }
}

// ---------------- policy head ----------------

__global__ void k_policy(const float* __restrict__ x, const float* __restrict__ Wp,
                         const float* __restrict__ bp, float* __restrict__ out, int n){
  __shared__ float Ws[64 * 8];
  __shared__ float bs[8];
  int t = threadIdx.x;
  for (int i = t; i < 64 * 8; i += blockDim.x) Ws[i] = Wp[i];
  if (t < 8) bs[t] = bp[t];
  __syncthreads();
  int idx = blockIdx.x * blockDim.x + t;
  if (idx >= n * 8) return;
  int node = idx >> 3, o = idx & 7;
  const float* xr = x + (size_t)node * 64;
  float acc = bs[o];
  #pragma unroll
  for (int k = 0; k < 64; k++) acc = fmaf(xr[k], Ws[k * 8 + o], acc);
  out[idx] = acc;
}

// ---------------- launch ----------------

extern "C" void kernel_launch(void* const* d_in, const int* in_sizes, int n_in,
                              void* d_out, int out_size, void* d_ws, size_t ws_size,
                              hipStream_t stream) {
  const float* x   = (const float*)d_in[0];
  const int*   ei  = (const int*)  d_in[1];
  const float* W1  = (const float*)d_in[2];
  const float* as1 = (const float*)d_in[3];
  const float* ad1 = (const float*)d_in[4];
  const float* b1  = (const float*)d_in[5];
  const float* W2  = (const float*)d_in[6];
  const float* as2 = (const float*)d_in[7];
  const float* ad2 = (const float*)d_in[8];
  const float* b2  = (const float*)d_in[9];
  const float* Wp  = (const float*)d_in[10];
  const float* bp  = (const float*)d_in[11];
  float* out = (float*)d_out;

  int N = in_sizes[0] / 16;
  int E = in_sizes[1] / 2;
  int TOT = E + N;
  int NB = (N + 255) >> 8;            // buckets of 256 dst nodes
  int T  = (TOT + TILE - 1) / TILE;   // edge tiles

  char* p = (char*)d_ws;
  auto alloc = [&](size_t bytes) -> char* {
    char* r = p; p += (bytes + 255) & ~(size_t)255; return r;
  };
  float* h      = (float*)alloc((size_t)N * 64 * 4);
  float* buf    = (float*)alloc((size_t)N * 64 * 4);
  float* sA     = (float*)alloc((size_t)N * 4);
  float* dA     = (float*)alloc((size_t)N * 4);
  int*   deg    = (int*)  alloc((size_t)N * 4);
  int*   rowptr = (int*)  alloc((size_t)(N + 1) * 4);
  int*   col    = (int*)  alloc((size_t)TOT * 4);
  int*   bsums  = (int*)  alloc(128 * 4);

  // scratch aliased onto h/buf (both are first written AFTER the CSR build)
  unsigned int* tmp  = (unsigned int*)h;           // TOT u32 <= N*64*4
  int*          Cmat = (int*)buf;                  // NB*T ints
  int*          Omat = Cmat + (size_t)NB * T;      // NB*T ints

  const int tb = 256;

  // CSR build (dst-grouped)
  (void)hipMemsetAsync(deg, 0, (size_t)N * 4, stream);
  k_hist<<<(TOT + tb - 1) / tb, tb, 0, stream>>>(ei, deg, E, N);
  int nb = (N + 1023) / 1024;
  k_scan_a<<<nb, 256, 0, stream>>>(deg, rowptr, bsums, N);
  k_scan_b<<<1, 128, 0, stream>>>(bsums, nb);
  k_scan_c<<<(N + 1 + tb - 1) / tb, tb, 0, stream>>>(rowptr, bsums, N, TOT);

  k_bcount<<<T, tb, 0, stream>>>(ei, Cmat, E, TOT, NB, T);
  k_bcolscan<<<(NB + 3) / 4, tb, 0, stream>>>(Cmat, rowptr, Omat, NB, T);
  k_bscatter<<<T, tb, 0, stream>>>(ei, Omat, tmp, E, TOT, NB, T);
  k_bfinal<<<NB, tb, 0, stream>>>(tmp, rowptr, col, N, TOT);

  // layer 1
  k_dense16<<<(N + 3) / 4, 256, 0, stream>>>(x, W1, as1, ad1, h, sA, dA, N);
  k_agg<<<(N + 3) / 4, 256, 0, stream>>>(h, sA, dA, rowptr, col, b1, buf, N);
  // layer 2
  k_dense64<<<(N + 3) / 4, 256, 0, stream>>>(buf, W2, as2, ad2, h, sA, dA, N);
  k_agg<<<(N + 3) / 4, 256, 0, stream>>>(h, sA, dA, rowptr, col, b2, buf, N);
  // policy head
  k_policy<<<((size_t)N * 8 + tb - 1) / tb, tb, 0, stream>>>(buf, Wp, bp, out, N);
}

// Round 5
// 320.905 us; speedup vs baseline: 2.1737x; 1.2305x over previous
//
#include <hip/hip_runtime.h>
#include <math.h>

#define NEG_SLOPE 0.2f
#define TILE 8192

__device__ __forceinline__ float wave_reduce_sum(float v){
  #pragma unroll
  for (int off = 32; off > 0; off >>= 1) v += __shfl_xor(v, off, 64);
  return v;
}
__device__ __forceinline__ float wave_reduce_max(float v){
  #pragma unroll
  for (int off = 32; off > 0; off >>= 1) v = fmaxf(v, __shfl_xor(v, off, 64));
  return v;
}

// ---------------- CSR build ----------------

__global__ void k_hist(const int* __restrict__ ei, int* __restrict__ deg, int E, int N){
  int e = blockIdx.x * blockDim.x + threadIdx.x;
  if (e >= E + N) return;
  int d = (e < E) ? ei[E + e] : (e - E);   // self loops appended after edges
  atomicAdd(&deg[d], 1);
}

__global__ void k_scan_a(const int* __restrict__ deg, int* __restrict__ rowptr,
                         int* __restrict__ bsums, int n){
  __shared__ int lds[256];
  int t = threadIdx.x;
  int base = blockIdx.x * 1024 + t * 4;
  int v[4]; int s = 0;
  #pragma unroll
  for (int i = 0; i < 4; i++){ int idx = base + i; v[i] = (idx < n) ? deg[idx] : 0; s += v[i]; }
  lds[t] = s; __syncthreads();
  for (int off = 1; off < 256; off <<= 1){
    int x = (t >= off) ? lds[t - off] : 0;
    __syncthreads();
    lds[t] += x;
    __syncthreads();
  }
  int excl = lds[t] - s;
  if (t == 255) bsums[blockIdx.x] = lds[255];
  int run = excl;
  #pragma unroll
  for (int i = 0; i < 4; i++){ int idx = base + i; if (idx < n) rowptr[idx] = run; run += v[i]; }
}

__global__ void k_scan_b(int* __restrict__ bsums, int nb){
  __shared__ int lds[128];
  int t = threadIdx.x;
  int v = (t < nb) ? bsums[t] : 0;
  lds[t] = v; __syncthreads();
  for (int off = 1; off < 128; off <<= 1){
    int x = (t >= off) ? lds[t - off] : 0;
    __syncthreads();
    lds[t] += x;
    __syncthreads();
  }
  if (t < nb) bsums[t] = lds[t] - v;
}

__global__ void k_scan_c(int* __restrict__ rowptr, const int* __restrict__ bsums,
                         int n, int total){
  int i = blockIdx.x * blockDim.x + threadIdx.x;
  if (i < n){
    rowptr[i] = rowptr[i] + bsums[i >> 10];
  } else if (i == n){
    rowptr[n] = total;
  }
}

// --- bucketed scatter: bucket = 256 consecutive dst nodes ---

__global__ void k_bcount(const int* __restrict__ ei, int* __restrict__ C,
                         int E, int TOT, int NB, int T){
  __shared__ int hist[512];
  int t = blockIdx.x;
  for (int i = threadIdx.x; i < NB; i += blockDim.x) hist[i] = 0;
  __syncthreads();
  int base = t * TILE;
  for (int k = threadIdx.x; k < TILE; k += blockDim.x){
    int j = base + k;
    if (j < TOT){
      int d = (j < E) ? ei[E + j] : (j - E);
      atomicAdd(&hist[d >> 8], 1);
    }
  }
  __syncthreads();
  for (int b = threadIdx.x; b < NB; b += blockDim.x) C[(size_t)b * T + t] = hist[b];
}

__global__ void k_bcolscan(const int* __restrict__ C, const int* __restrict__ rowptr,
                           int* __restrict__ O, int NB, int T){
  int wid = (blockIdx.x * blockDim.x + threadIdx.x) >> 6;
  int lane = threadIdx.x & 63;
  if (wid >= NB) return;
  int run = rowptr[wid << 8];
  int nchunks = (T + 63) / 64;
  for (int i = 0; i < nchunks; i++){
    int t = i * 64 + lane;
    int v = (t < T) ? C[(size_t)wid * T + t] : 0;
    int s = v;
    #pragma unroll
    for (int off = 1; off < 64; off <<= 1){
      int u = __shfl_up(s, off);
      if (lane >= off) s += u;
    }
    if (t < T) O[(size_t)wid * T + t] = run + (s - v);
    run += __shfl(s, 63);
  }
}

__global__ void k_bscatter(const int* __restrict__ ei, const int* __restrict__ O,
                           unsigned int* __restrict__ tmp, int E, int TOT, int NB, int T){
  __shared__ int cur[512];
  int t = blockIdx.x;
  for (int b = threadIdx.x; b < NB; b += blockDim.x) cur[b] = O[(size_t)b * T + t];
  __syncthreads();
  int base = t * TILE;
  for (int k = threadIdx.x; k < TILE; k += blockDim.x){
    int j = base + k;
    if (j < TOT){
      int s, d;
      if (j < E){ s = ei[j]; d = ei[E + j]; } else { s = j - E; d = s; }
      int r = atomicAdd(&cur[d >> 8], 1);
      tmp[r] = ((unsigned)s << 8) | (unsigned)(d & 255);
    }
  }
}

__global__ void k_bfinal(const unsigned int* __restrict__ tmp, const int* __restrict__ rowptr,
                         int* __restrict__ col, int N, int TOT){
  __shared__ int cur[256];
  int b = blockIdx.x;
  int base_node = b << 8;
  int nnode = min(256, N - base_node);
  if ((int)threadIdx.x < nnode) cur[threadIdx.x] = rowptr[base_node + threadIdx.x];
  __syncthreads();
  int beg = rowptr[base_node];
  int end = rowptr[base_node + nnode];
  for (int j = beg + (int)threadIdx.x; j < end; j += blockDim.x){
    unsigned v = tmp[j];
    int pos = atomicAdd(&cur[v & 255u], 1);
    col[pos] = (int)(v >> 8);
  }
}

// ---------------- dense ops (register-blocked: thread = node-half) ----------------

// K=16: h = x @ W1 (N x 16 @ 16 x 64), plus s,d
__global__ void k_dense16(const float* __restrict__ x, const float* __restrict__ W,
                          const float* __restrict__ asrc, const float* __restrict__ adst,
                          float* __restrict__ h, float* __restrict__ sarr, float* __restrict__ darr,
                          int n){
  __shared__ float4 Ws4[16 * 16];   // W[k][c] as float4 over c
  __shared__ float as_s[64], ad_s[64];
  int t = threadIdx.x;
  const float4* W4 = (const float4*)W;
  if (t < 256){ if (t < 16 * 16) Ws4[t] = W4[t]; }
  if (t < 64){ as_s[t] = asrc[t]; ad_s[t] = adst[t]; }
  __syncthreads();
  int gid = blockIdx.x * blockDim.x + t;
  int node = gid >> 1;
  int half = gid & 1;
  if (node >= n) return;
  const float4* xr = (const float4*)(x + (size_t)node * 16);
  float4 acc[8] = {};
  #pragma unroll
  for (int kk = 0; kk < 4; kk++){
    float4 xv = xr[kk];
    #pragma unroll
    for (int i = 0; i < 4; i++){
      float xk = (i == 0) ? xv.x : (i == 1) ? xv.y : (i == 2) ? xv.z : xv.w;
      const float4* wrow = &Ws4[(kk * 4 + i) * 16 + half * 8];
      #pragma unroll
      for (int c = 0; c < 8; c++){
        acc[c].x = fmaf(xk, wrow[c].x, acc[c].x);
        acc[c].y = fmaf(xk, wrow[c].y, acc[c].y);
        acc[c].z = fmaf(xk, wrow[c].z, acc[c].z);
        acc[c].w = fmaf(xk, wrow[c].w, acc[c].w);
      }
    }
  }
  float4* hr = (float4*)(h + (size_t)node * 64 + half * 32);
  float sv = 0.f, dv = 0.f;
  #pragma unroll
  for (int c = 0; c < 8; c++){
    hr[c] = acc[c];
    int cb = half * 32 + c * 4;
    sv += acc[c].x * as_s[cb] + acc[c].y * as_s[cb+1] + acc[c].z * as_s[cb+2] + acc[c].w * as_s[cb+3];
    dv += acc[c].x * ad_s[cb] + acc[c].y * ad_s[cb+1] + acc[c].z * ad_s[cb+2] + acc[c].w * ad_s[cb+3];
  }
  sv += __shfl_xor(sv, 1);
  dv += __shfl_xor(dv, 1);
  if (half == 0){ sarr[node] = sv; darr[node] = dv; }
}

// K=64: h = x @ W (N x 64 @ 64 x 64), plus s,d
__global__ void k_dense64(const float* __restrict__ x, const float* __restrict__ W,
                          const float* __restrict__ asrc, const float* __restrict__ adst,
                          float* __restrict__ h, float* __restrict__ sarr, float* __restrict__ darr,
                          int n){
  __shared__ float4 Ws4[64 * 16];   // 16 KB
  __shared__ float as_s[64], ad_s[64];
  int t = threadIdx.x;
  const float4* W4 = (const float4*)W;
  for (int i = t; i < 64 * 16; i += blockDim.x) Ws4[i] = W4[i];
  if (t < 64){ as_s[t] = asrc[t]; ad_s[t] = adst[t]; }
  __syncthreads();
  int gid = blockIdx.x * blockDim.x + t;
  int node = gid >> 1;
  int half = gid & 1;
  if (node >= n) return;
  const float4* xr = (const float4*)(x + (size_t)node * 64);
  float4 acc[8] = {};
  #pragma unroll
  for (int kk = 0; kk < 16; kk++){
    float4 xv = xr[kk];
    #pragma unroll
    for (int i = 0; i < 4; i++){
      float xk = (i == 0) ? xv.x : (i == 1) ? xv.y : (i == 2) ? xv.z : xv.w;
      const float4* wrow = &Ws4[(kk * 4 + i) * 16 + half * 8];
      #pragma unroll
      for (int c = 0; c < 8; c++){
        acc[c].x = fmaf(xk, wrow[c].x, acc[c].x);
        acc[c].y = fmaf(xk, wrow[c].y, acc[c].y);
        acc[c].z = fmaf(xk, wrow[c].z, acc[c].z);
        acc[c].w = fmaf(xk, wrow[c].w, acc[c].w);
      }
    }
  }
  float4* hr = (float4*)(h + (size_t)node * 64 + half * 32);
  float sv = 0.f, dv = 0.f;
  #pragma unroll
  for (int c = 0; c < 8; c++){
    hr[c] = acc[c];
    int cb = half * 32 + c * 4;
    sv += acc[c].x * as_s[cb] + acc[c].y * as_s[cb+1] + acc[c].z * as_s[cb+2] + acc[c].w * as_s[cb+3];
    dv += acc[c].x * ad_s[cb] + acc[c].y * ad_s[cb+1] + acc[c].z * ad_s[cb+2] + acc[c].w * ad_s[cb+3];
  }
  sv += __shfl_xor(sv, 1);
  dv += __shfl_xor(dv, 1);
  if (half == 0){ sarr[node] = sv; darr[node] = dv; }
}

// ---------------- GAT softmax-aggregate (wave per node) ----------------

__global__ void k_agg(const float* __restrict__ h, const float* __restrict__ sarr,
                      const float* __restrict__ darr, const int* __restrict__ rowptr,
                      const int* __restrict__ col, const float* __restrict__ bias,
                      float* __restrict__ out, int n){
  int node = blockIdx.x * (blockDim.x >> 6) + (threadIdx.x >> 6);
  if (node >= n) return;
  int lane = threadIdx.x & 63;
  int beg = rowptr[node], end = rowptr[node + 1];
  int deg = end - beg;
  float dn = darr[node];

  if (deg <= 128){
    int c0 = 0, c1 = 0;
    float e0 = -INFINITY, e1 = -INFINITY;
    if (lane < deg){
      c0 = col[beg + lane];
      float t = sarr[c0] + dn;
      e0 = (t > 0.f) ? t : NEG_SLOPE * t;
    }
    if (lane + 64 < deg){
      c1 = col[beg + lane + 64];
      float t = sarr[c1] + dn;
      e1 = (t > 0.f) ? t : NEG_SLOPE * t;
    }
    float m = wave_reduce_max(fmaxf(e0, e1));
    float w0 = (lane < deg)      ? __expf(e0 - m) : 0.f;
    float w1 = (lane + 64 < deg) ? __expf(e1 - m) : 0.f;
    float sum = wave_reduce_sum(w0 + w1);
    float inv = 1.f / (sum + 1e-16f);
    float a0 = w0 * inv, a1 = w1 * inv;

    int eg = lane >> 4, cq = lane & 15;
    float4 acc = make_float4(0.f, 0.f, 0.f, 0.f);
    for (int j0 = 0; j0 < deg; j0 += 4){
      int idx = j0 + eg;
      int sl = idx & 63;
      int   sA = __shfl(c0, sl);
      int   sB = __shfl(c1, sl);
      float aA = __shfl(a0, sl);
      float aB = __shfl(a1, sl);
      int   s  = (idx & 64) ? sB : sA;
      float a  = (idx & 64) ? aB : aA;
      if (idx < deg){
        const float4 hv = *(const float4*)(h + (size_t)s * 64 + cq * 4);
        acc.x = fmaf(a, hv.x, acc.x);
        acc.y = fmaf(a, hv.y, acc.y);
        acc.z = fmaf(a, hv.z, acc.z);
        acc.w = fmaf(a, hv.w, acc.w);
      }
    }
    acc.x += __shfl_xor(acc.x, 16); acc.x += __shfl_xor(acc.x, 32);
    acc.y += __shfl_xor(acc.y, 16); acc.y += __shfl_xor(acc.y, 32);
    acc.z += __shfl_xor(acc.z, 16); acc.z += __shfl_xor(acc.z, 32);
    acc.w += __shfl_xor(acc.w, 16); acc.w += __shfl_xor(acc.w, 32);
    if (eg == 0){
      const float4 bv = *(const float4*)(bias + cq * 4);
      float4 r;
      r.x = fmaxf(acc.x + bv.x, 0.f);
      r.y = fmaxf(acc.y + bv.y, 0.f);
      r.z = fmaxf(acc.z + bv.z, 0.f);
      r.w = fmaxf(acc.w + bv.w, 0.f);
      *(float4*)(out + (size_t)node * 64 + cq * 4) = r;
    }
  } else {
    float m = -INFINITY;
    for (int j = beg + lane; j < end; j += 64){
      float e = sarr[col[j]] + dn;
      e = (e > 0.f) ? e : NEG_SLOPE * e;
      m = fmaxf(m, e);
    }
    m = wave_reduce_max(m);
    float sum = 0.f;
    for (int j = beg + lane; j < end; j += 64){
      float e = sarr[col[j]] + dn;
      e = (e > 0.f) ? e : NEG_SLOPE * e;
      sum += __expf(e - m);
    }
    sum = wave_reduce_sum(sum);
    float invden = 1.0f / (sum + 1e-16f);
    float acc = 0.f;
    for (int j = beg; j < end; j++){
      int s = col[j];
      float e = sarr[s] + dn;
      e = (e > 0.f) ? e : NEG_SLOPE * e;
      float alpha = __expf(e - m) * invden;
      acc = fmaf(alpha, h[(size_t)s * 64 + lane], acc);
    }
    float r = acc + bias[lane];
    out[(size_t)node * 64 + lane] = fmaxf(r, 0.f);
  }
}

// ---------------- policy head ----------------

__global__ void k_policy(const float* __restrict__ x, const float* __restrict__ Wp,
                         const float* __restrict__ bp, float* __restrict__ out, int n){
  __shared__ float Ws[64 * 8];
  __shared__ float bs[8];
  int t = threadIdx.x;
  for (int i = t; i < 64 * 8; i += blockDim.x) Ws[i] = Wp[i];
  if (t < 8) bs[t] = bp[t];
  __syncthreads();
  int idx = blockIdx.x * blockDim.x + t;
  if (idx >= n * 8) return;
  int node = idx >> 3, o = idx & 7;
  const float* xr = x + (size_t)node * 64;
  float acc = bs[o];
  #pragma unroll
  for (int k = 0; k < 64; k++) acc = fmaf(xr[k], Ws[k * 8 + o], acc);
  out[idx] = acc;
}

// ---------------- launch ----------------

extern "C" void kernel_launch(void* const* d_in, const int* in_sizes, int n_in,
                              void* d_out, int out_size, void* d_ws, size_t ws_size,
                              hipStream_t stream) {
  const float* x   = (const float*)d_in[0];
  const int*   ei  = (const int*)  d_in[1];
  const float* W1  = (const float*)d_in[2];
  const float* as1 = (const float*)d_in[3];
  const float* ad1 = (const float*)d_in[4];
  const float* b1  = (const float*)d_in[5];
  const float* W2  = (const float*)d_in[6];
  const float* as2 = (const float*)d_in[7];
  const float* ad2 = (const float*)d_in[8];
  const float* b2  = (const float*)d_in[9];
  const float* Wp  = (const float*)d_in[10];
  const float* bp  = (const float*)d_in[11];
  float* out = (float*)d_out;

  int N = in_sizes[0] / 16;
  int E = in_sizes[1] / 2;
  int TOT = E + N;
  int NB = (N + 255) >> 8;            // buckets of 256 dst nodes
  int T  = (TOT + TILE - 1) / TILE;   // edge tiles

  char* p = (char*)d_ws;
  auto alloc = [&](size_t bytes) -> char* {
    char* r = p; p += (bytes + 255) & ~(size_t)255; return r;
  };
  float* h      = (float*)alloc((size_t)N * 64 * 4);
  float* buf    = (float*)alloc((size_t)N * 64 * 4);
  float* sA     = (float*)alloc((size_t)N * 4);
  float* dA     = (float*)alloc((size_t)N * 4);
  int*   deg    = (int*)  alloc((size_t)N * 4);
  int*   rowptr = (int*)  alloc((size_t)(N + 1) * 4);
  int*   col    = (int*)  alloc((size_t)TOT * 4);
  int*   bsums  = (int*)  alloc(128 * 4);

  // scratch aliased onto h/buf (both are first written AFTER the CSR build)
  unsigned int* tmp  = (unsigned int*)h;           // TOT u32 <= N*64*4
  int*          Cmat = (int*)buf;                  // NB*T ints
  int*          Omat = Cmat + (size_t)NB * T;      // NB*T ints

  const int tb = 256;

  // CSR build (dst-grouped)
  (void)hipMemsetAsync(deg, 0, (size_t)N * 4, stream);
  k_hist<<<(TOT + tb - 1) / tb, tb, 0, stream>>>(ei, deg, E, N);
  int nb = (N + 1023) / 1024;
  k_scan_a<<<nb, 256, 0, stream>>>(deg, rowptr, bsums, N);
  k_scan_b<<<1, 128, 0, stream>>>(bsums, nb);
  k_scan_c<<<(N + 1 + tb - 1) / tb, tb, 0, stream>>>(rowptr, bsums, N, TOT);

  k_bcount<<<T, tb, 0, stream>>>(ei, Cmat, E, TOT, NB, T);
  k_bcolscan<<<(NB + 3) / 4, tb, 0, stream>>>(Cmat, rowptr, Omat, NB, T);
  k_bscatter<<<T, tb, 0, stream>>>(ei, Omat, tmp, E, TOT, NB, T);
  k_bfinal<<<NB, tb, 0, stream>>>(tmp, rowptr, col, N, TOT);

  // layer 1
  k_dense16<<<(2 * N + tb - 1) / tb, tb, 0, stream>>>(x, W1, as1, ad1, h, sA, dA, N);
  k_agg<<<(N + 3) / 4, 256, 0, stream>>>(h, sA, dA, rowptr, col, b1, buf, N);
  // layer 2
  k_dense64<<<(2 * N + tb - 1) / tb, tb, 0, stream>>>(buf, W2, as2, ad2, h, sA, dA, N);
  k_agg<<<(N + 3) / 4, 256, 0, stream>>>(h, sA, dA, rowptr, col, b2, buf, N);
  // policy head
  k_policy<<<((size_t)N * 8 + tb - 1) / tb, tb, 0, stream>>>(buf, Wp, bp, out, N);
}

// Round 7
// 318.783 us; speedup vs baseline: 2.1882x; 1.0067x over previous
//
#include <hip/hip_runtime.h>
#include <hip/hip_fp16.h>
#include <math.h>

#define NEG_SLOPE 0.2f
#define TILE 8192

__device__ __forceinline__ float wave_reduce_sum(float v){
  #pragma unroll
  for (int off = 32; off > 0; off >>= 1) v += __shfl_xor(v, off, 64);
  return v;
}
__device__ __forceinline__ float wave_reduce_max(float v){
  #pragma unroll
  for (int off = 32; off > 0; off >>= 1) v = fmaxf(v, __shfl_xor(v, off, 64));
  return v;
}

// ---------------- CSR build ----------------

__global__ void k_hist(const int* __restrict__ ei, int* __restrict__ deg, int E, int N){
  int e = blockIdx.x * blockDim.x + threadIdx.x;
  if (e >= E + N) return;
  int d = (e < E) ? ei[E + e] : (e - E);   // self loops appended after edges
  atomicAdd(&deg[d], 1);
}

__global__ void k_scan_a(const int* __restrict__ deg, int* __restrict__ rowptr,
                         int* __restrict__ bsums, int n){
  __shared__ int lds[256];
  int t = threadIdx.x;
  int base = blockIdx.x * 1024 + t * 4;
  int v[4]; int s = 0;
  #pragma unroll
  for (int i = 0; i < 4; i++){ int idx = base + i; v[i] = (idx < n) ? deg[idx] : 0; s += v[i]; }
  lds[t] = s; __syncthreads();
  for (int off = 1; off < 256; off <<= 1){
    int x = (t >= off) ? lds[t - off] : 0;
    __syncthreads();
    lds[t] += x;
    __syncthreads();
  }
  int excl = lds[t] - s;
  if (t == 255) bsums[blockIdx.x] = lds[255];
  int run = excl;
  #pragma unroll
  for (int i = 0; i < 4; i++){ int idx = base + i; if (idx < n) rowptr[idx] = run; run += v[i]; }
}

__global__ void k_scan_b(int* __restrict__ bsums, int nb){
  __shared__ int lds[128];
  int t = threadIdx.x;
  int v = (t < nb) ? bsums[t] : 0;
  lds[t] = v; __syncthreads();
  for (int off = 1; off < 128; off <<= 1){
    int x = (t >= off) ? lds[t - off] : 0;
    __syncthreads();
    lds[t] += x;
    __syncthreads();
  }
  if (t < nb) bsums[t] = lds[t] - v;
}

__global__ void k_scan_c(int* __restrict__ rowptr, const int* __restrict__ bsums,
                         int n, int total){
  int i = blockIdx.x * blockDim.x + threadIdx.x;
  if (i < n){
    rowptr[i] = rowptr[i] + bsums[i >> 10];
  } else if (i == n){
    rowptr[n] = total;
  }
}

// --- bucketed scatter: bucket = 256 consecutive dst nodes ---

__global__ void k_bcount(const int* __restrict__ ei, int* __restrict__ C,
                         int E, int TOT, int NB, int T){
  __shared__ int hist[512];
  int t = blockIdx.x;
  for (int i = threadIdx.x; i < NB; i += blockDim.x) hist[i] = 0;
  __syncthreads();
  int base = t * TILE;
  for (int k = threadIdx.x; k < TILE; k += blockDim.x){
    int j = base + k;
    if (j < TOT){
      int d = (j < E) ? ei[E + j] : (j - E);
      atomicAdd(&hist[d >> 8], 1);
    }
  }
  __syncthreads();
  for (int b = threadIdx.x; b < NB; b += blockDim.x) C[(size_t)b * T + t] = hist[b];
}

__global__ void k_bcolscan(const int* __restrict__ C, const int* __restrict__ rowptr,
                           int* __restrict__ O, int NB, int T){
  int wid = (blockIdx.x * blockDim.x + threadIdx.x) >> 6;
  int lane = threadIdx.x & 63;
  if (wid >= NB) return;
  int run = rowptr[wid << 8];
  int nchunks = (T + 63) / 64;
  for (int i = 0; i < nchunks; i++){
    int t = i * 64 + lane;
    int v = (t < T) ? C[(size_t)wid * T + t] : 0;
    int s = v;
    #pragma unroll
    for (int off = 1; off < 64; off <<= 1){
      int u = __shfl_up(s, off);
      if (lane >= off) s += u;
    }
    if (t < T) O[(size_t)wid * T + t] = run + (s - v);
    run += __shfl(s, 63);
  }
}

__global__ void k_bscatter(const int* __restrict__ ei, const int* __restrict__ O,
                           unsigned int* __restrict__ tmp, int E, int TOT, int NB, int T){
  __shared__ int cur[512];
  int t = blockIdx.x;
  for (int b = threadIdx.x; b < NB; b += blockDim.x) cur[b] = O[(size_t)b * T + t];
  __syncthreads();
  int base = t * TILE;
  for (int k = threadIdx.x; k < TILE; k += blockDim.x){
    int j = base + k;
    if (j < TOT){
      int s, d;
      if (j < E){ s = ei[j]; d = ei[E + j]; } else { s = j - E; d = s; }
      int r = atomicAdd(&cur[d >> 8], 1);
      tmp[r] = ((unsigned)s << 8) | (unsigned)(d & 255);
    }
  }
}

__global__ void k_bfinal(const unsigned int* __restrict__ tmp, const int* __restrict__ rowptr,
                         int* __restrict__ col, int N, int TOT){
  __shared__ int cur[256];
  int b = blockIdx.x;
  int base_node = b << 8;
  int nnode = min(256, N - base_node);
  if ((int)threadIdx.x < nnode) cur[threadIdx.x] = rowptr[base_node + threadIdx.x];
  __syncthreads();
  int beg = rowptr[base_node];
  int end = rowptr[base_node + nnode];
  for (int j = beg + (int)threadIdx.x; j < end; j += blockDim.x){
    unsigned v = tmp[j];
    int pos = atomicAdd(&cur[v & 255u], 1);
    col[pos] = (int)(v >> 8);
  }
}

// ---------------- dense ops (register-blocked; h output in fp16) ----------------

__global__ void k_dense16(const float* __restrict__ x, const float* __restrict__ W,
                          const float* __restrict__ asrc, const float* __restrict__ adst,
                          __half* __restrict__ h16, float* __restrict__ sarr, float* __restrict__ darr,
                          int n){
  __shared__ float4 Ws4[16 * 16];
  __shared__ float as_s[64], ad_s[64];
  int t = threadIdx.x;
  const float4* W4 = (const float4*)W;
  if (t < 16 * 16) Ws4[t] = W4[t];
  if (t < 64){ as_s[t] = asrc[t]; ad_s[t] = adst[t]; }
  __syncthreads();
  int gid = blockIdx.x * blockDim.x + t;
  int node = gid >> 1;
  int half = gid & 1;
  if (node >= n) return;
  const float4* xr = (const float4*)(x + (size_t)node * 16);
  float4 acc[8] = {};
  #pragma unroll
  for (int kk = 0; kk < 4; kk++){
    float4 xv = xr[kk];
    #pragma unroll
    for (int i = 0; i < 4; i++){
      float xk = (i == 0) ? xv.x : (i == 1) ? xv.y : (i == 2) ? xv.z : xv.w;
      const float4* wrow = &Ws4[(kk * 4 + i) * 16 + half * 8];
      #pragma unroll
      for (int c = 0; c < 8; c++){
        acc[c].x = fmaf(xk, wrow[c].x, acc[c].x);
        acc[c].y = fmaf(xk, wrow[c].y, acc[c].y);
        acc[c].z = fmaf(xk, wrow[c].z, acc[c].z);
        acc[c].w = fmaf(xk, wrow[c].w, acc[c].w);
      }
    }
  }
  float sv = 0.f, dv = 0.f;
  #pragma unroll
  for (int c = 0; c < 8; c += 2){
    union { __half2 h2[4]; uint4 u; } pk;
    pk.h2[0] = __floats2half2_rn(acc[c].x,   acc[c].y);
    pk.h2[1] = __floats2half2_rn(acc[c].z,   acc[c].w);
    pk.h2[2] = __floats2half2_rn(acc[c+1].x, acc[c+1].y);
    pk.h2[3] = __floats2half2_rn(acc[c+1].z, acc[c+1].w);
    *(uint4*)(h16 + (size_t)node * 64 + half * 32 + c * 4) = pk.u;
  }
  #pragma unroll
  for (int c = 0; c < 8; c++){
    int cb = half * 32 + c * 4;
    sv += acc[c].x * as_s[cb] + acc[c].y * as_s[cb+1] + acc[c].z * as_s[cb+2] + acc[c].w * as_s[cb+3];
    dv += acc[c].x * ad_s[cb] + acc[c].y * ad_s[cb+1] + acc[c].z * ad_s[cb+2] + acc[c].w * ad_s[cb+3];
  }
  sv += __shfl_xor(sv, 1);
  dv += __shfl_xor(dv, 1);
  if (half == 0){ sarr[node] = sv; darr[node] = dv; }
}

__global__ void k_dense64(const float* __restrict__ x, const float* __restrict__ W,
                          const float* __restrict__ asrc, const float* __restrict__ adst,
                          __half* __restrict__ h16, float* __restrict__ sarr, float* __restrict__ darr,
                          int n){
  __shared__ float4 Ws4[64 * 16];   // 16 KB
  __shared__ float as_s[64], ad_s[64];
  int t = threadIdx.x;
  const float4* W4 = (const float4*)W;
  for (int i = t; i < 64 * 16; i += blockDim.x) Ws4[i] = W4[i];
  if (t < 64){ as_s[t] = asrc[t]; ad_s[t] = adst[t]; }
  __syncthreads();
  int gid = blockIdx.x * blockDim.x + t;
  int node = gid >> 1;
  int half = gid & 1;
  if (node >= n) return;
  const float4* xr = (const float4*)(x + (size_t)node * 64);
  float4 acc[8] = {};
  #pragma unroll
  for (int kk = 0; kk < 16; kk++){
    float4 xv = xr[kk];
    #pragma unroll
    for (int i = 0; i < 4; i++){
      float xk = (i == 0) ? xv.x : (i == 1) ? xv.y : (i == 2) ? xv.z : xv.w;
      const float4* wrow = &Ws4[(kk * 4 + i) * 16 + half * 8];
      #pragma unroll
      for (int c = 0; c < 8; c++){
        acc[c].x = fmaf(xk, wrow[c].x, acc[c].x);
        acc[c].y = fmaf(xk, wrow[c].y, acc[c].y);
        acc[c].z = fmaf(xk, wrow[c].z, acc[c].z);
        acc[c].w = fmaf(xk, wrow[c].w, acc[c].w);
      }
    }
  }
  float sv = 0.f, dv = 0.f;
  #pragma unroll
  for (int c = 0; c < 8; c += 2){
    union { __half2 h2[4]; uint4 u; } pk;
    pk.h2[0] = __floats2half2_rn(acc[c].x,   acc[c].y);
    pk.h2[1] = __floats2half2_rn(acc[c].z,   acc[c].w);
    pk.h2[2] = __floats2half2_rn(acc[c+1].x, acc[c+1].y);
    pk.h2[3] = __floats2half2_rn(acc[c+1].z, acc[c+1].w);
    *(uint4*)(h16 + (size_t)node * 64 + half * 32 + c * 4) = pk.u;
  }
  #pragma unroll
  for (int c = 0; c < 8; c++){
    int cb = half * 32 + c * 4;
    sv += acc[c].x * as_s[cb] + acc[c].y * as_s[cb+1] + acc[c].z * as_s[cb+2] + acc[c].w * as_s[cb+3];
    dv += acc[c].x * ad_s[cb] + acc[c].y * ad_s[cb+1] + acc[c].z * ad_s[cb+2] + acc[c].w * ad_s[cb+3];
  }
  sv += __shfl_xor(sv, 1);
  dv += __shfl_xor(dv, 1);
  if (half == 0){ sarr[node] = sv; darr[node] = dv; }
}

// ---------------- GAT softmax-aggregate (wave per node, fp16 h) ----------------

__device__ __forceinline__ void agg_softmax(const float* sarr, const int* col,
                                            int beg, int deg, float dn, int lane,
                                            int& c0, int& c1, float& a0, float& a1){
  c0 = 0; c1 = 0;
  float e0 = -INFINITY, e1 = -INFINITY;
  if (lane < deg){
    c0 = col[beg + lane];
    float t = sarr[c0] + dn;
    e0 = (t > 0.f) ? t : NEG_SLOPE * t;
  }
  if (lane + 64 < deg){
    c1 = col[beg + lane + 64];
    float t = sarr[c1] + dn;
    e1 = (t > 0.f) ? t : NEG_SLOPE * t;
  }
  float m = wave_reduce_max(fmaxf(e0, e1));
  float w0 = (lane < deg)      ? __expf(e0 - m) : 0.f;
  float w1 = (lane + 64 < deg) ? __expf(e1 - m) : 0.f;
  float sum = wave_reduce_sum(w0 + w1);
  float inv = 1.f / (sum + 1e-16f);
  a0 = w0 * inv; a1 = w1 * inv;
}

__device__ __forceinline__ float4 agg_gather(const __half* h16, int deg, int lane,
                                             int c0, int c1, float a0, float a1){
  int eg = lane >> 4, cq = lane & 15;
  float4 acc = make_float4(0.f, 0.f, 0.f, 0.f);
  for (int j0 = 0; j0 < deg; j0 += 4){
    int idx = j0 + eg;
    int sl = idx & 63;
    int   sA = __shfl(c0, sl);
    int   sB = __shfl(c1, sl);
    float aA = __shfl(a0, sl);
    float aB = __shfl(a1, sl);
    int   s  = (idx & 64) ? sB : sA;
    float a  = (idx & 64) ? aB : aA;
    if (idx < deg){
      float2 raw = *(const float2*)(h16 + (size_t)s * 64 + cq * 4);
      __half2 ha = *(__half2*)&raw.x;
      __half2 hb = *(__half2*)&raw.y;
      float2 f0 = __half22float2(ha);
      float2 f1 = __half22float2(hb);
      acc.x = fmaf(a, f0.x, acc.x);
      acc.y = fmaf(a, f0.y, acc.y);
      acc.z = fmaf(a, f1.x, acc.z);
      acc.w = fmaf(a, f1.y, acc.w);
    }
  }
  acc.x += __shfl_xor(acc.x, 16); acc.x += __shfl_xor(acc.x, 32);
  acc.y += __shfl_xor(acc.y, 16); acc.y += __shfl_xor(acc.y, 32);
  acc.z += __shfl_xor(acc.z, 16); acc.z += __shfl_xor(acc.z, 32);
  acc.w += __shfl_xor(acc.w, 16); acc.w += __shfl_xor(acc.w, 32);
  return acc;
}

// layer-1: writes relu(agg + bias) as fp32 [N][64]
__global__ void k_agg1(const __half* __restrict__ h16, const float* __restrict__ sarr,
                       const float* __restrict__ darr, const int* __restrict__ rowptr,
                       const int* __restrict__ col, const float* __restrict__ bias,
                       float* __restrict__ out, int n){
  int node = blockIdx.x * (blockDim.x >> 6) + (threadIdx.x >> 6);
  if (node >= n) return;
  int lane = threadIdx.x & 63;
  int beg = rowptr[node], end = rowptr[node + 1];
  int deg = end - beg;
  float dn = darr[node];

  if (deg <= 128){
    int c0, c1; float a0, a1;
    agg_softmax(sarr, col, beg, deg, dn, lane, c0, c1, a0, a1);
    float4 acc = agg_gather(h16, deg, lane, c0, c1, a0, a1);
    int eg = lane >> 4, cq = lane & 15;
    if (eg == 0){
      const float4 bv = *(const float4*)(bias + cq * 4);
      float4 r;
      r.x = fmaxf(acc.x + bv.x, 0.f);
      r.y = fmaxf(acc.y + bv.y, 0.f);
      r.z = fmaxf(acc.z + bv.z, 0.f);
      r.w = fmaxf(acc.w + bv.w, 0.f);
      *(float4*)(out + (size_t)node * 64 + cq * 4) = r;
    }
  } else {
    float m = -INFINITY;
    for (int j = beg + lane; j < end; j += 64){
      float e = sarr[col[j]] + dn;
      e = (e > 0.f) ? e : NEG_SLOPE * e;
      m = fmaxf(m, e);
    }
    m = wave_reduce_max(m);
    float sum = 0.f;
    for (int j = beg + lane; j < end; j += 64){
      float e = sarr[col[j]] + dn;
      e = (e > 0.f) ? e : NEG_SLOPE * e;
      sum += __expf(e - m);
    }
    sum = wave_reduce_sum(sum);
    float invden = 1.0f / (sum + 1e-16f);
    float acc = 0.f;
    for (int j = beg; j < end; j++){
      int s = col[j];
      float e = sarr[s] + dn;
      e = (e > 0.f) ? e : NEG_SLOPE * e;
      float alpha = __expf(e - m) * invden;
      acc = fmaf(alpha, __half2float(h16[(size_t)s * 64 + lane]), acc);
    }
    float r = acc + bias[lane];
    out[(size_t)node * 64 + lane] = fmaxf(r, 0.f);
  }
}

// layer-2 + fused policy head: writes [N][8] fp32
__global__ void k_agg2(const __half* __restrict__ h16, const float* __restrict__ sarr,
                       const float* __restrict__ darr, const int* __restrict__ rowptr,
                       const int* __restrict__ col, const float* __restrict__ bias,
                       const float* __restrict__ Wp, const float* __restrict__ bp,
                       float* __restrict__ out, int n){
  __shared__ float Wp_s[8 * 64];   // transposed: [o][c]
  __shared__ float bp_s[8];
  {
    int t = threadIdx.x;
    for (int i = t; i < 512; i += blockDim.x)      // FIX: 512 elems, 256 threads
      Wp_s[(i & 7) * 64 + (i >> 3)] = Wp[i];
    if (t < 8) bp_s[t] = bp[t];
  }
  __syncthreads();
  int node = blockIdx.x * (blockDim.x >> 6) + (threadIdx.x >> 6);
  if (node >= n) return;
  int lane = threadIdx.x & 63;
  int beg = rowptr[node], end = rowptr[node + 1];
  int deg = end - beg;
  float dn = darr[node];

  if (deg <= 128){
    int c0, c1; float a0, a1;
    agg_softmax(sarr, col, beg, deg, dn, lane, c0, c1, a0, a1);
    float4 acc = agg_gather(h16, deg, lane, c0, c1, a0, a1);
    int eg = lane >> 4, cq = lane & 15;
    if (eg == 0){
      const float4 bv = *(const float4*)(bias + cq * 4);
      float r0 = fmaxf(acc.x + bv.x, 0.f);
      float r1 = fmaxf(acc.y + bv.y, 0.f);
      float r2 = fmaxf(acc.z + bv.z, 0.f);
      float r3 = fmaxf(acc.w + bv.w, 0.f);
      float po[8];
      #pragma unroll
      for (int o = 0; o < 8; o++){
        const float* wr = &Wp_s[o * 64 + cq * 4];
        po[o] = r0 * wr[0] + r1 * wr[1] + r2 * wr[2] + r3 * wr[3];
      }
      #pragma unroll
      for (int off = 1; off < 16; off <<= 1){
        #pragma unroll
        for (int o = 0; o < 8; o++) po[o] += __shfl_xor(po[o], off);
      }
      if (cq == 0){
        float4 y0 = make_float4(po[0] + bp_s[0], po[1] + bp_s[1], po[2] + bp_s[2], po[3] + bp_s[3]);
        float4 y1 = make_float4(po[4] + bp_s[4], po[5] + bp_s[5], po[6] + bp_s[6], po[7] + bp_s[7]);
        *(float4*)(out + (size_t)node * 8)     = y0;
        *(float4*)(out + (size_t)node * 8 + 4) = y1;
      }
    }
  } else {
    float m = -INFINITY;
    for (int j = beg + lane; j < end; j += 64){
      float e = sarr[col[j]] + dn;
      e = (e > 0.f) ? e : NEG_SLOPE * e;
      m = fmaxf(m, e);
    }
    m = wave_reduce_max(m);
    float sum = 0.f;
    for (int j = beg + lane; j < end; j += 64){
      float e = sarr[col[j]] + dn;
      e = (e > 0.f) ? e : NEG_SLOPE * e;
      sum += __expf(e - m);
    }
    sum = wave_reduce_sum(sum);
    float invden = 1.0f / (sum + 1e-16f);
    float acc = 0.f;
    for (int j = beg; j < end; j++){
      int s = col[j];
      float e = sarr[s] + dn;
      e = (e > 0.f) ? e : NEG_SLOPE * e;
      float alpha = __expf(e - m) * invden;
      acc = fmaf(alpha, __half2float(h16[(size_t)s * 64 + lane]), acc);
    }
    float r = fmaxf(acc + bias[lane], 0.f);
    #pragma unroll
    for (int o = 0; o < 8; o++){
      float po = wave_reduce_sum(r * Wp_s[o * 64 + lane]);
      if (lane == 0) out[(size_t)node * 8 + o] = po + bp_s[o];
    }
  }
}

// ---------------- launch ----------------

extern "C" void kernel_launch(void* const* d_in, const int* in_sizes, int n_in,
                              void* d_out, int out_size, void* d_ws, size_t ws_size,
                              hipStream_t stream) {
  const float* x   = (const float*)d_in[0];
  const int*   ei  = (const int*)  d_in[1];
  const float* W1  = (const float*)d_in[2];
  const float* as1 = (const float*)d_in[3];
  const float* ad1 = (const float*)d_in[4];
  const float* b1  = (const float*)d_in[5];
  const float* W2  = (const float*)d_in[6];
  const float* as2 = (const float*)d_in[7];
  const float* ad2 = (const float*)d_in[8];
  const float* b2  = (const float*)d_in[9];
  const float* Wp  = (const float*)d_in[10];
  const float* bp  = (const float*)d_in[11];
  float* out = (float*)d_out;

  int N = in_sizes[0] / 16;
  int E = in_sizes[1] / 2;
  int TOT = E + N;
  int NB = (N + 255) >> 8;            // buckets of 256 dst nodes
  int T  = (TOT + TILE - 1) / TILE;   // edge tiles

  char* p = (char*)d_ws;
  auto alloc = [&](size_t bytes) -> char* {
    char* r = p; p += (bytes + 255) & ~(size_t)255; return r;
  };
  __half* h16   = (__half*)alloc((size_t)N * 64 * 2);
  float* buf    = (float*)alloc((size_t)N * 64 * 4);
  float* sA     = (float*)alloc((size_t)N * 4);
  float* dA     = (float*)alloc((size_t)N * 4);
  int*   deg    = (int*)  alloc((size_t)N * 4);
  int*   rowptr = (int*)  alloc((size_t)(N + 1) * 4);
  int*   col    = (int*)  alloc((size_t)TOT * 4);
  int*   bsums  = (int*)  alloc(128 * 4);

  // scratch aliased onto h16/buf (both first written AFTER the CSR build)
  unsigned int* tmp  = (unsigned int*)h16;         // TOT u32 <= N*64*2 (6.8MB < 12.8MB)
  int*          Cmat = (int*)buf;                  // NB*T ints
  int*          Omat = Cmat + (size_t)NB * T;      // NB*T ints

  const int tb = 256;

  // CSR build (dst-grouped)
  (void)hipMemsetAsync(deg, 0, (size_t)N * 4, stream);
  k_hist<<<(TOT + tb - 1) / tb, tb, 0, stream>>>(ei, deg, E, N);
  int nb = (N + 1023) / 1024;
  k_scan_a<<<nb, 256, 0, stream>>>(deg, rowptr, bsums, N);
  k_scan_b<<<1, 128, 0, stream>>>(bsums, nb);
  k_scan_c<<<(N + 1 + tb - 1) / tb, tb, 0, stream>>>(rowptr, bsums, N, TOT);

  k_bcount<<<T, tb, 0, stream>>>(ei, Cmat, E, TOT, NB, T);
  k_bcolscan<<<(NB + 3) / 4, tb, 0, stream>>>(Cmat, rowptr, Omat, NB, T);
  k_bscatter<<<T, tb, 0, stream>>>(ei, Omat, tmp, E, TOT, NB, T);
  k_bfinal<<<NB, tb, 0, stream>>>(tmp, rowptr, col, N, TOT);

  // layer 1
  k_dense16<<<(2 * N + tb - 1) / tb, tb, 0, stream>>>(x, W1, as1, ad1, h16, sA, dA, N);
  k_agg1<<<(N + 3) / 4, 256, 0, stream>>>(h16, sA, dA, rowptr, col, b1, buf, N);
  // layer 2 (+ fused policy head)
  k_dense64<<<(2 * N + tb - 1) / tb, tb, 0, stream>>>(buf, W2, as2, ad2, h16, sA, dA, N);
  k_agg2<<<(N + 3) / 4, 256, 0, stream>>>(h16, sA, dA, rowptr, col, b2, Wp, bp, out, N);
}

// Round 8
// 290.961 us; speedup vs baseline: 2.3974x; 1.0956x over previous
//
#include <hip/hip_runtime.h>
#include <hip/hip_fp16.h>
#include <math.h>

#define NEG_SLOPE 0.2f
#define TILE 8192

__device__ __forceinline__ float wave_reduce_sum(float v){
  #pragma unroll
  for (int off = 32; off > 0; off >>= 1) v += __shfl_xor(v, off, 64);
  return v;
}
__device__ __forceinline__ float wave_reduce_max(float v){
  #pragma unroll
  for (int off = 32; off > 0; off >>= 1) v = fmaxf(v, __shfl_xor(v, off, 64));
  return v;
}

// ---------------- CSR build ----------------

__global__ void k_hist(const int* __restrict__ ei, int* __restrict__ deg, int E, int N){
  int e = blockIdx.x * blockDim.x + threadIdx.x;
  if (e >= E + N) return;
  int d = (e < E) ? ei[E + e] : (e - E);   // self loops appended after edges
  atomicAdd(&deg[d], 1);
}

__global__ void k_scan_a(const int* __restrict__ deg, int* __restrict__ rowptr,
                         int* __restrict__ bsums, int n){
  __shared__ int lds[256];
  int t = threadIdx.x;
  int base = blockIdx.x * 1024 + t * 4;
  int v[4]; int s = 0;
  #pragma unroll
  for (int i = 0; i < 4; i++){ int idx = base + i; v[i] = (idx < n) ? deg[idx] : 0; s += v[i]; }
  lds[t] = s; __syncthreads();
  for (int off = 1; off < 256; off <<= 1){
    int x = (t >= off) ? lds[t - off] : 0;
    __syncthreads();
    lds[t] += x;
    __syncthreads();
  }
  int excl = lds[t] - s;
  if (t == 255) bsums[blockIdx.x] = lds[255];
  int run = excl;
  #pragma unroll
  for (int i = 0; i < 4; i++){ int idx = base + i; if (idx < n) rowptr[idx] = run; run += v[i]; }
}

__global__ void k_scan_b(int* __restrict__ bsums, int nb){
  __shared__ int lds[128];
  int t = threadIdx.x;
  int v = (t < nb) ? bsums[t] : 0;
  lds[t] = v; __syncthreads();
  for (int off = 1; off < 128; off <<= 1){
    int x = (t >= off) ? lds[t - off] : 0;
    __syncthreads();
    lds[t] += x;
    __syncthreads();
  }
  if (t < nb) bsums[t] = lds[t] - v;
}

__global__ void k_scan_c(int* __restrict__ rowptr, const int* __restrict__ bsums,
                         int n, int total){
  int i = blockIdx.x * blockDim.x + threadIdx.x;
  if (i < n){
    rowptr[i] = rowptr[i] + bsums[i >> 10];
  } else if (i == n){
    rowptr[n] = total;
  }
}

// --- bucketed scatter: bucket = 256 consecutive dst nodes ---

__global__ void k_bcount(const int* __restrict__ ei, int* __restrict__ C,
                         int E, int TOT, int NB, int T){
  __shared__ int hist[512];
  int t = blockIdx.x;
  for (int i = threadIdx.x; i < NB; i += blockDim.x) hist[i] = 0;
  __syncthreads();
  int base = t * TILE;
  for (int k = threadIdx.x; k < TILE; k += blockDim.x){
    int j = base + k;
    if (j < TOT){
      int d = (j < E) ? ei[E + j] : (j - E);
      atomicAdd(&hist[d >> 8], 1);
    }
  }
  __syncthreads();
  for (int b = threadIdx.x; b < NB; b += blockDim.x) C[(size_t)b * T + t] = hist[b];
}

__global__ void k_bcolscan(const int* __restrict__ C, const int* __restrict__ rowptr,
                           int* __restrict__ O, int NB, int T){
  int wid = (blockIdx.x * blockDim.x + threadIdx.x) >> 6;
  int lane = threadIdx.x & 63;
  if (wid >= NB) return;
  int run = rowptr[wid << 8];
  int nchunks = (T + 63) / 64;
  for (int i = 0; i < nchunks; i++){
    int t = i * 64 + lane;
    int v = (t < T) ? C[(size_t)wid * T + t] : 0;
    int s = v;
    #pragma unroll
    for (int off = 1; off < 64; off <<= 1){
      int u = __shfl_up(s, off);
      if (lane >= off) s += u;
    }
    if (t < T) O[(size_t)wid * T + t] = run + (s - v);
    run += __shfl(s, 63);
  }
}

__global__ void k_bscatter(const int* __restrict__ ei, const int* __restrict__ O,
                           unsigned int* __restrict__ tmp, int E, int TOT, int NB, int T){
  __shared__ int cur[512];
  int t = blockIdx.x;
  for (int b = threadIdx.x; b < NB; b += blockDim.x) cur[b] = O[(size_t)b * T + t];
  __syncthreads();
  int base = t * TILE;
  for (int k = threadIdx.x; k < TILE; k += blockDim.x){
    int j = base + k;
    if (j < TOT){
      int s, d;
      if (j < E){ s = ei[j]; d = ei[E + j]; } else { s = j - E; d = s; }
      int r = atomicAdd(&cur[d >> 8], 1);
      tmp[r] = ((unsigned)s << 8) | (unsigned)(d & 255);
    }
  }
}

__global__ void k_bfinal(const unsigned int* __restrict__ tmp, const int* __restrict__ rowptr,
                         int* __restrict__ col, int N, int TOT){
  __shared__ int cur[256];
  int b = blockIdx.x;
  int base_node = b << 8;
  int nnode = min(256, N - base_node);
  if ((int)threadIdx.x < nnode) cur[threadIdx.x] = rowptr[base_node + threadIdx.x];
  __syncthreads();
  int beg = rowptr[base_node];
  int end = rowptr[base_node + nnode];
  for (int j = beg + (int)threadIdx.x; j < end; j += blockDim.x){
    unsigned v = tmp[j];
    int pos = atomicAdd(&cur[v & 255u], 1);
    col[pos] = (int)(v >> 8);
  }
}

// ---------------- dense ops (register-blocked; h output in fp16) ----------------

__global__ void k_dense16(const float* __restrict__ x, const float* __restrict__ W,
                          const float* __restrict__ asrc, const float* __restrict__ adst,
                          __half* __restrict__ h16, float* __restrict__ sarr, float* __restrict__ darr,
                          int n){
  __shared__ float4 Ws4[16 * 16];
  __shared__ float as_s[64], ad_s[64];
  int t = threadIdx.x;
  const float4* W4 = (const float4*)W;
  if (t < 16 * 16) Ws4[t] = W4[t];
  if (t < 64){ as_s[t] = asrc[t]; ad_s[t] = adst[t]; }
  __syncthreads();
  int gid = blockIdx.x * blockDim.x + t;
  int node = gid >> 1;
  int half = gid & 1;
  if (node >= n) return;
  const float4* xr = (const float4*)(x + (size_t)node * 16);
  float4 acc[8] = {};
  #pragma unroll
  for (int kk = 0; kk < 4; kk++){
    float4 xv = xr[kk];
    #pragma unroll
    for (int i = 0; i < 4; i++){
      float xk = (i == 0) ? xv.x : (i == 1) ? xv.y : (i == 2) ? xv.z : xv.w;
      const float4* wrow = &Ws4[(kk * 4 + i) * 16 + half * 8];
      #pragma unroll
      for (int c = 0; c < 8; c++){
        acc[c].x = fmaf(xk, wrow[c].x, acc[c].x);
        acc[c].y = fmaf(xk, wrow[c].y, acc[c].y);
        acc[c].z = fmaf(xk, wrow[c].z, acc[c].z);
        acc[c].w = fmaf(xk, wrow[c].w, acc[c].w);
      }
    }
  }
  float sv = 0.f, dv = 0.f;
  #pragma unroll
  for (int c = 0; c < 8; c += 2){
    union { __half2 h2[4]; uint4 u; } pk;
    pk.h2[0] = __floats2half2_rn(acc[c].x,   acc[c].y);
    pk.h2[1] = __floats2half2_rn(acc[c].z,   acc[c].w);
    pk.h2[2] = __floats2half2_rn(acc[c+1].x, acc[c+1].y);
    pk.h2[3] = __floats2half2_rn(acc[c+1].z, acc[c+1].w);
    *(uint4*)(h16 + (size_t)node * 64 + half * 32 + c * 4) = pk.u;
  }
  #pragma unroll
  for (int c = 0; c < 8; c++){
    int cb = half * 32 + c * 4;
    sv += acc[c].x * as_s[cb] + acc[c].y * as_s[cb+1] + acc[c].z * as_s[cb+2] + acc[c].w * as_s[cb+3];
    dv += acc[c].x * ad_s[cb] + acc[c].y * ad_s[cb+1] + acc[c].z * ad_s[cb+2] + acc[c].w * ad_s[cb+3];
  }
  sv += __shfl_xor(sv, 1);
  dv += __shfl_xor(dv, 1);
  if (half == 0){ sarr[node] = sv; darr[node] = dv; }
}

__global__ void k_dense64(const float* __restrict__ x, const float* __restrict__ W,
                          const float* __restrict__ asrc, const float* __restrict__ adst,
                          __half* __restrict__ h16, float* __restrict__ sarr, float* __restrict__ darr,
                          int n){
  __shared__ float4 Ws4[64 * 16];   // 16 KB
  __shared__ float as_s[64], ad_s[64];
  int t = threadIdx.x;
  const float4* W4 = (const float4*)W;
  for (int i = t; i < 64 * 16; i += blockDim.x) Ws4[i] = W4[i];
  if (t < 64){ as_s[t] = asrc[t]; ad_s[t] = adst[t]; }
  __syncthreads();
  int gid = blockIdx.x * blockDim.x + t;
  int node = gid >> 1;
  int half = gid & 1;
  if (node >= n) return;
  const float4* xr = (const float4*)(x + (size_t)node * 64);
  float4 acc[8] = {};
  #pragma unroll
  for (int kk = 0; kk < 16; kk++){
    float4 xv = xr[kk];
    #pragma unroll
    for (int i = 0; i < 4; i++){
      float xk = (i == 0) ? xv.x : (i == 1) ? xv.y : (i == 2) ? xv.z : xv.w;
      const float4* wrow = &Ws4[(kk * 4 + i) * 16 + half * 8];
      #pragma unroll
      for (int c = 0; c < 8; c++){
        acc[c].x = fmaf(xk, wrow[c].x, acc[c].x);
        acc[c].y = fmaf(xk, wrow[c].y, acc[c].y);
        acc[c].z = fmaf(xk, wrow[c].z, acc[c].z);
        acc[c].w = fmaf(xk, wrow[c].w, acc[c].w);
      }
    }
  }
  float sv = 0.f, dv = 0.f;
  #pragma unroll
  for (int c = 0; c < 8; c += 2){
    union { __half2 h2[4]; uint4 u; } pk;
    pk.h2[0] = __floats2half2_rn(acc[c].x,   acc[c].y);
    pk.h2[1] = __floats2half2_rn(acc[c].z,   acc[c].w);
    pk.h2[2] = __floats2half2_rn(acc[c+1].x, acc[c+1].y);
    pk.h2[3] = __floats2half2_rn(acc[c+1].z, acc[c+1].w);
    *(uint4*)(h16 + (size_t)node * 64 + half * 32 + c * 4) = pk.u;
  }
  #pragma unroll
  for (int c = 0; c < 8; c++){
    int cb = half * 32 + c * 4;
    sv += acc[c].x * as_s[cb] + acc[c].y * as_s[cb+1] + acc[c].z * as_s[cb+2] + acc[c].w * as_s[cb+3];
    dv += acc[c].x * ad_s[cb] + acc[c].y * ad_s[cb+1] + acc[c].z * ad_s[cb+2] + acc[c].w * ad_s[cb+3];
  }
  sv += __shfl_xor(sv, 1);
  dv += __shfl_xor(dv, 1);
  if (half == 0){ sarr[node] = sv; darr[node] = dv; }
}

// ---------------- GAT softmax-aggregate (wave per node, fp16 h, LDS stash) ----------------

__device__ __forceinline__ void agg_softmax(const float* sarr, const int* col,
                                            int beg, int deg, float dn, int lane,
                                            int& c0, int& c1, float& a0, float& a1){
  c0 = 0; c1 = 0;
  float e0 = -INFINITY, e1 = -INFINITY;
  if (lane < deg){
    c0 = col[beg + lane];
    float t = sarr[c0] + dn;
    e0 = (t > 0.f) ? t : NEG_SLOPE * t;
  }
  if (lane + 64 < deg){
    c1 = col[beg + lane + 64];
    float t = sarr[c1] + dn;
    e1 = (t > 0.f) ? t : NEG_SLOPE * t;
  }
  float m = wave_reduce_max(fmaxf(e0, e1));
  float w0 = (lane < deg)      ? __expf(e0 - m) : 0.f;
  float w1 = (lane + 64 < deg) ? __expf(e1 - m) : 0.f;
  float sum = wave_reduce_sum(w0 + w1);
  float inv = 1.f / (sum + 1e-16f);
  a0 = w0 * inv; a1 = w1 * inv;
}

// gather reading (col,alpha) pairs from per-wave LDS stash; butterfly leaves the
// full cq-group sum in EVERY lane.
__device__ __forceinline__ float4 agg_gather_lds(const __half* h16, int deg, int lane,
                                                 const int2* stash){
  int eg = lane >> 4, cq = lane & 15;
  float4 acc = make_float4(0.f, 0.f, 0.f, 0.f);
  #pragma unroll 2
  for (int j0 = 0; j0 < deg; j0 += 4){
    int idx = j0 + eg;
    if (idx < deg){
      int2 ca = stash[idx];
      float a = __int_as_float(ca.y);
      float2 raw = *(const float2*)(h16 + (size_t)ca.x * 64 + cq * 4);
      __half2 ha = *(__half2*)&raw.x;
      __half2 hb = *(__half2*)&raw.y;
      float2 f0 = __half22float2(ha);
      float2 f1 = __half22float2(hb);
      acc.x = fmaf(a, f0.x, acc.x);
      acc.y = fmaf(a, f0.y, acc.y);
      acc.z = fmaf(a, f1.x, acc.z);
      acc.w = fmaf(a, f1.y, acc.w);
    }
  }
  acc.x += __shfl_xor(acc.x, 16); acc.x += __shfl_xor(acc.x, 32);
  acc.y += __shfl_xor(acc.y, 16); acc.y += __shfl_xor(acc.y, 32);
  acc.z += __shfl_xor(acc.z, 16); acc.z += __shfl_xor(acc.z, 32);
  acc.w += __shfl_xor(acc.w, 16); acc.w += __shfl_xor(acc.w, 32);
  return acc;
}

// layer-1: writes relu(agg + bias) as fp32 [N][64]
__global__ void k_agg1(const __half* __restrict__ h16, const float* __restrict__ sarr,
                       const float* __restrict__ darr, const int* __restrict__ rowptr,
                       const int* __restrict__ col, const float* __restrict__ bias,
                       float* __restrict__ out, int n){
  __shared__ int2 stash[4][128];
  int w = threadIdx.x >> 6;
  int lane = threadIdx.x & 63;
  int node = blockIdx.x * (blockDim.x >> 6) + w;
  bool valid = node < n;
  int beg = 0, deg = 0; float dn = 0.f;
  if (valid){ beg = rowptr[node]; deg = rowptr[node + 1] - beg; dn = darr[node]; }
  bool fast = valid && (deg <= 128);

  if (fast){
    int c0, c1; float a0, a1;
    agg_softmax(sarr, col, beg, deg, dn, lane, c0, c1, a0, a1);
    if (lane < deg)      stash[w][lane]      = make_int2(c0, __float_as_int(a0));
    if (lane + 64 < deg) stash[w][lane + 64] = make_int2(c1, __float_as_int(a1));
  }
  __syncthreads();
  if (fast){
    float4 acc = agg_gather_lds(h16, deg, lane, stash[w]);
    int eg = lane >> 4, cq = lane & 15;
    if (eg == 0){
      const float4 bv = *(const float4*)(bias + cq * 4);
      float4 r;
      r.x = fmaxf(acc.x + bv.x, 0.f);
      r.y = fmaxf(acc.y + bv.y, 0.f);
      r.z = fmaxf(acc.z + bv.z, 0.f);
      r.w = fmaxf(acc.w + bv.w, 0.f);
      *(float4*)(out + (size_t)node * 64 + cq * 4) = r;
    }
  } else if (valid){
    float m = -INFINITY;
    int end = beg + deg;
    for (int j = beg + lane; j < end; j += 64){
      float e = sarr[col[j]] + dn;
      e = (e > 0.f) ? e : NEG_SLOPE * e;
      m = fmaxf(m, e);
    }
    m = wave_reduce_max(m);
    float sum = 0.f;
    for (int j = beg + lane; j < end; j += 64){
      float e = sarr[col[j]] + dn;
      e = (e > 0.f) ? e : NEG_SLOPE * e;
      sum += __expf(e - m);
    }
    sum = wave_reduce_sum(sum);
    float invden = 1.0f / (sum + 1e-16f);
    float acc = 0.f;
    for (int j = beg; j < end; j++){
      int s = col[j];
      float e = sarr[s] + dn;
      e = (e > 0.f) ? e : NEG_SLOPE * e;
      float alpha = __expf(e - m) * invden;
      acc = fmaf(alpha, __half2float(h16[(size_t)s * 64 + lane]), acc);
    }
    float r = acc + bias[lane];
    out[(size_t)node * 64 + lane] = fmaxf(r, 0.f);
  }
}

// layer-2 + fused policy head: writes [N][8] fp32. Wp in registers (8/lane).
__global__ void k_agg2(const __half* __restrict__ h16, const float* __restrict__ sarr,
                       const float* __restrict__ darr, const int* __restrict__ rowptr,
                       const int* __restrict__ col, const float* __restrict__ bias,
                       const float* __restrict__ Wp, const float* __restrict__ bp,
                       float* __restrict__ out, int n){
  __shared__ int2 stash[4][128];
  int w = threadIdx.x >> 6;
  int lane = threadIdx.x & 63;
  int o = lane & 7, g = lane >> 3;
  // per-lane slice of Wp: wp[j] = Wp[c][o] with c = g*8+j  (Wp row-major [64][8])
  float wp[8];
  #pragma unroll
  for (int j = 0; j < 8; j++) wp[j] = Wp[(g * 8 + j) * 8 + o];
  float bpv = bp[o];

  int node = blockIdx.x * (blockDim.x >> 6) + w;
  bool valid = node < n;
  int beg = 0, deg = 0; float dn = 0.f;
  if (valid){ beg = rowptr[node]; deg = rowptr[node + 1] - beg; dn = darr[node]; }
  bool fast = valid && (deg <= 128);

  if (fast){
    int c0, c1; float a0, a1;
    agg_softmax(sarr, col, beg, deg, dn, lane, c0, c1, a0, a1);
    if (lane < deg)      stash[w][lane]      = make_int2(c0, __float_as_int(a0));
    if (lane + 64 < deg) stash[w][lane + 64] = make_int2(c1, __float_as_int(a1));
  }
  __syncthreads();
  if (fast){
    float4 acc = agg_gather_lds(h16, deg, lane, stash[w]);
    int cq = lane & 15;
    const float4 bv = *(const float4*)(bias + cq * 4);
    float4 r;
    r.x = fmaxf(acc.x + bv.x, 0.f);
    r.y = fmaxf(acc.y + bv.y, 0.f);
    r.z = fmaxf(acc.z + bv.z, 0.f);
    r.w = fmaxf(acc.w + bv.w, 0.f);
    // channels c=g*8..g*8+7 live as float4 on lanes 2g (c%8<4) and 2g+1
    int s0 = g * 2, s1 = g * 2 + 1;
    float po;
    po  = __shfl(r.x, s0) * wp[0];
    po += __shfl(r.y, s0) * wp[1];
    po += __shfl(r.z, s0) * wp[2];
    po += __shfl(r.w, s0) * wp[3];
    po += __shfl(r.x, s1) * wp[4];
    po += __shfl(r.y, s1) * wp[5];
    po += __shfl(r.z, s1) * wp[6];
    po += __shfl(r.w, s1) * wp[7];
    po += __shfl_xor(po, 8);
    po += __shfl_xor(po, 16);
    po += __shfl_xor(po, 32);
    if (lane < 8) out[(size_t)node * 8 + lane] = po + bpv;
  } else if (valid){
    int end = beg + deg;
    float m = -INFINITY;
    for (int j = beg + lane; j < end; j += 64){
      float e = sarr[col[j]] + dn;
      e = (e > 0.f) ? e : NEG_SLOPE * e;
      m = fmaxf(m, e);
    }
    m = wave_reduce_max(m);
    float sum = 0.f;
    for (int j = beg + lane; j < end; j += 64){
      float e = sarr[col[j]] + dn;
      e = (e > 0.f) ? e : NEG_SLOPE * e;
      sum += __expf(e - m);
    }
    sum = wave_reduce_sum(sum);
    float invden = 1.0f / (sum + 1e-16f);
    float acc = 0.f;
    for (int j = beg; j < end; j++){
      int s = col[j];
      float e = sarr[s] + dn;
      e = (e > 0.f) ? e : NEG_SLOPE * e;
      float alpha = __expf(e - m) * invden;
      acc = fmaf(alpha, __half2float(h16[(size_t)s * 64 + lane]), acc);
    }
    float r = fmaxf(acc + bias[lane], 0.f);   // channel = lane
    float po = 0.f;
    #pragma unroll
    for (int j = 0; j < 8; j++) po += __shfl(r, g * 8 + j) * wp[j];
    po += __shfl_xor(po, 8);
    po += __shfl_xor(po, 16);
    po += __shfl_xor(po, 32);
    if (lane < 8) out[(size_t)node * 8 + lane] = po + bpv;
  }
}

// ---------------- launch ----------------

extern "C" void kernel_launch(void* const* d_in, const int* in_sizes, int n_in,
                              void* d_out, int out_size, void* d_ws, size_t ws_size,
                              hipStream_t stream) {
  const float* x   = (const float*)d_in[0];
  const int*   ei  = (const int*)  d_in[1];
  const float* W1  = (const float*)d_in[2];
  const float* as1 = (const float*)d_in[3];
  const float* ad1 = (const float*)d_in[4];
  const float* b1  = (const float*)d_in[5];
  const float* W2  = (const float*)d_in[6];
  const float* as2 = (const float*)d_in[7];
  const float* ad2 = (const float*)d_in[8];
  const float* b2  = (const float*)d_in[9];
  const float* Wp  = (const float*)d_in[10];
  const float* bp  = (const float*)d_in[11];
  float* out = (float*)d_out;

  int N = in_sizes[0] / 16;
  int E = in_sizes[1] / 2;
  int TOT = E + N;
  int NB = (N + 255) >> 8;            // buckets of 256 dst nodes
  int T  = (TOT + TILE - 1) / TILE;   // edge tiles

  char* p = (char*)d_ws;
  auto alloc = [&](size_t bytes) -> char* {
    char* r = p; p += (bytes + 255) & ~(size_t)255; return r;
  };
  __half* h16   = (__half*)alloc((size_t)N * 64 * 2);
  float* buf    = (float*)alloc((size_t)N * 64 * 4);
  float* sA     = (float*)alloc((size_t)N * 4);
  float* dA     = (float*)alloc((size_t)N * 4);
  int*   deg    = (int*)  alloc((size_t)N * 4);
  int*   rowptr = (int*)  alloc((size_t)(N + 1) * 4);
  int*   col    = (int*)  alloc((size_t)TOT * 4);
  int*   bsums  = (int*)  alloc(128 * 4);

  // scratch aliased onto h16/buf (both first written AFTER the CSR build)
  unsigned int* tmp  = (unsigned int*)h16;         // TOT u32 <= N*64*2 (6.8MB < 12.8MB)
  int*          Cmat = (int*)buf;                  // NB*T ints
  int*          Omat = Cmat + (size_t)NB * T;      // NB*T ints

  const int tb = 256;

  // CSR build (dst-grouped)
  (void)hipMemsetAsync(deg, 0, (size_t)N * 4, stream);
  k_hist<<<(TOT + tb - 1) / tb, tb, 0, stream>>>(ei, deg, E, N);
  int nb = (N + 1023) / 1024;
  k_scan_a<<<nb, 256, 0, stream>>>(deg, rowptr, bsums, N);
  k_scan_b<<<1, 128, 0, stream>>>(bsums, nb);
  k_scan_c<<<(N + 1 + tb - 1) / tb, tb, 0, stream>>>(rowptr, bsums, N, TOT);

  k_bcount<<<T, tb, 0, stream>>>(ei, Cmat, E, TOT, NB, T);
  k_bcolscan<<<(NB + 3) / 4, tb, 0, stream>>>(Cmat, rowptr, Omat, NB, T);
  k_bscatter<<<T, tb, 0, stream>>>(ei, Omat, tmp, E, TOT, NB, T);
  k_bfinal<<<NB, tb, 0, stream>>>(tmp, rowptr, col, N, TOT);

  // layer 1
  k_dense16<<<(2 * N + tb - 1) / tb, tb, 0, stream>>>(x, W1, as1, ad1, h16, sA, dA, N);
  k_agg1<<<(N + 3) / 4, 256, 0, stream>>>(h16, sA, dA, rowptr, col, b1, buf, N);
  // layer 2 (+ fused policy head)
  k_dense64<<<(2 * N + tb - 1) / tb, tb, 0, stream>>>(buf, W2, as2, ad2, h16, sA, dA, N);
  k_agg2<<<(N + 3) / 4, 256, 0, stream>>>(h16, sA, dA, rowptr, col, b2, Wp, bp, out, N);
}

// Round 9
// 243.070 us; speedup vs baseline: 2.8698x; 1.1970x over previous
//
#include <hip/hip_runtime.h>
#include <hip/hip_fp16.h>
#include <math.h>

#define NEG_SLOPE 0.2f
#define TILE 8192
// assumes NB = ceil(N/256) <= 512 (N <= 131072)

__device__ __forceinline__ float wave_reduce_sum(float v){
  #pragma unroll
  for (int off = 32; off > 0; off >>= 1) v += __shfl_xor(v, off, 64);
  return v;
}
__device__ __forceinline__ float wave_reduce_max(float v){
  #pragma unroll
  for (int off = 32; off > 0; off >>= 1) v = fmaxf(v, __shfl_xor(v, off, 64));
  return v;
}

// ---------------- CSR build (bucketed; no global hist/scan chain) ----------------

__global__ void k_bcount(const int* __restrict__ ei, int* __restrict__ C,
                         int E, int TOT, int NB, int T){
  __shared__ int hist[512];
  int t = blockIdx.x;
  for (int i = threadIdx.x; i < NB; i += blockDim.x) hist[i] = 0;
  __syncthreads();
  int base = t * TILE;
  for (int k = threadIdx.x; k < TILE; k += blockDim.x){
    int j = base + k;
    if (j < TOT){
      int d = (j < E) ? ei[E + j] : (j - E);
      atomicAdd(&hist[d >> 8], 1);
    }
  }
  __syncthreads();
  for (int b = threadIdx.x; b < NB; b += blockDim.x) C[(size_t)b * T + t] = hist[b];
}

// 1 block, 512 threads: bucket totals from C, exclusive scan -> Bstart
__global__ void k_bstart(const int* __restrict__ C, int* __restrict__ Bstart,
                         int* __restrict__ rowptr, int NB, int T, int TOT, int N){
  __shared__ int lds[512];
  int t = threadIdx.x;
  int total = 0;
  if (t < NB){
    const int* row = C + (size_t)t * T;
    for (int i = 0; i < T; i++) total += row[i];
  }
  lds[t] = total; __syncthreads();
  for (int off = 1; off < 512; off <<= 1){
    int x = (t >= off) ? lds[t - off] : 0;
    __syncthreads();
    lds[t] += x;
    __syncthreads();
  }
  if (t < NB) Bstart[t] = lds[t] - total;   // exclusive
  if (t == 0){ Bstart[NB] = TOT; rowptr[N] = TOT; }
}

__global__ void k_bcolscan(const int* __restrict__ C, const int* __restrict__ Bstart,
                           int* __restrict__ O, int NB, int T){
  int wid = (blockIdx.x * blockDim.x + threadIdx.x) >> 6;
  int lane = threadIdx.x & 63;
  if (wid >= NB) return;
  int run = Bstart[wid];
  int nchunks = (T + 63) / 64;
  for (int i = 0; i < nchunks; i++){
    int t = i * 64 + lane;
    int v = (t < T) ? C[(size_t)wid * T + t] : 0;
    int s = v;
    #pragma unroll
    for (int off = 1; off < 64; off <<= 1){
      int u = __shfl_up(s, off);
      if (lane >= off) s += u;
    }
    if (t < T) O[(size_t)wid * T + t] = run + (s - v);
    run += __shfl(s, 63);
  }
}

__global__ void k_bscatter(const int* __restrict__ ei, const int* __restrict__ O,
                           unsigned int* __restrict__ tmp, int E, int TOT, int NB, int T){
  __shared__ int cur[512];
  int t = blockIdx.x;
  for (int b = threadIdx.x; b < NB; b += blockDim.x) cur[b] = O[(size_t)b * T + t];
  __syncthreads();
  int base = t * TILE;
  for (int k = threadIdx.x; k < TILE; k += blockDim.x){
    int j = base + k;
    if (j < TOT){
      int s, d;
      if (j < E){ s = ei[j]; d = ei[E + j]; } else { s = j - E; d = s; }
      int r = atomicAdd(&cur[d >> 8], 1);
      tmp[r] = ((unsigned)s << 8) | (unsigned)(d & 255);
    }
  }
}

// per bucket: in-LDS degree histogram + scan -> rowptr AND final col scatter
__global__ void k_bfinal(const unsigned int* __restrict__ tmp, const int* __restrict__ Bstart,
                         int* __restrict__ rowptr, int* __restrict__ col, int N){
  __shared__ int hist[256];
  __shared__ int sc[256];
  __shared__ int cur[256];
  int b = blockIdx.x;
  int base_node = b << 8;
  int nnode = min(256, N - base_node);
  int beg = Bstart[b], end = Bstart[b + 1];
  int t = threadIdx.x;
  hist[t] = 0;
  __syncthreads();
  for (int j = beg + t; j < end; j += blockDim.x)
    atomicAdd(&hist[tmp[j] & 255u], 1);
  __syncthreads();
  int v = hist[t];
  sc[t] = v; __syncthreads();
  for (int off = 1; off < 256; off <<= 1){
    int x = (t >= off) ? sc[t - off] : 0;
    __syncthreads();
    sc[t] += x;
    __syncthreads();
  }
  int excl = sc[t] - v;
  if (t < nnode) rowptr[base_node + t] = beg + excl;
  cur[t] = beg + excl;
  __syncthreads();
  for (int j = beg + t; j < end; j += blockDim.x){
    unsigned u = tmp[j];
    int pos = atomicAdd(&cur[u & 255u], 1);
    col[pos] = (int)(u >> 8);
  }
}

// ---------------- dense ops (register-blocked; h output in fp16) ----------------

__global__ void k_dense16(const float* __restrict__ x, const float* __restrict__ W,
                          const float* __restrict__ asrc, const float* __restrict__ adst,
                          __half* __restrict__ h16, float* __restrict__ sarr, float* __restrict__ darr,
                          int n){
  __shared__ float4 Ws4[16 * 16];
  __shared__ float as_s[64], ad_s[64];
  int t = threadIdx.x;
  const float4* W4 = (const float4*)W;
  if (t < 16 * 16) Ws4[t] = W4[t];
  if (t < 64){ as_s[t] = asrc[t]; ad_s[t] = adst[t]; }
  __syncthreads();
  int gid = blockIdx.x * blockDim.x + t;
  int node = gid >> 1;
  int half = gid & 1;
  if (node >= n) return;
  const float4* xr = (const float4*)(x + (size_t)node * 16);
  float4 acc[8] = {};
  #pragma unroll
  for (int kk = 0; kk < 4; kk++){
    float4 xv = xr[kk];
    #pragma unroll
    for (int i = 0; i < 4; i++){
      float xk = (i == 0) ? xv.x : (i == 1) ? xv.y : (i == 2) ? xv.z : xv.w;
      const float4* wrow = &Ws4[(kk * 4 + i) * 16 + half * 8];
      #pragma unroll
      for (int c = 0; c < 8; c++){
        acc[c].x = fmaf(xk, wrow[c].x, acc[c].x);
        acc[c].y = fmaf(xk, wrow[c].y, acc[c].y);
        acc[c].z = fmaf(xk, wrow[c].z, acc[c].z);
        acc[c].w = fmaf(xk, wrow[c].w, acc[c].w);
      }
    }
  }
  float sv = 0.f, dv = 0.f;
  #pragma unroll
  for (int c = 0; c < 8; c += 2){
    union { __half2 h2[4]; uint4 u; } pk;
    pk.h2[0] = __floats2half2_rn(acc[c].x,   acc[c].y);
    pk.h2[1] = __floats2half2_rn(acc[c].z,   acc[c].w);
    pk.h2[2] = __floats2half2_rn(acc[c+1].x, acc[c+1].y);
    pk.h2[3] = __floats2half2_rn(acc[c+1].z, acc[c+1].w);
    *(uint4*)(h16 + (size_t)node * 64 + half * 32 + c * 4) = pk.u;
  }
  #pragma unroll
  for (int c = 0; c < 8; c++){
    int cb = half * 32 + c * 4;
    sv += acc[c].x * as_s[cb] + acc[c].y * as_s[cb+1] + acc[c].z * as_s[cb+2] + acc[c].w * as_s[cb+3];
    dv += acc[c].x * ad_s[cb] + acc[c].y * ad_s[cb+1] + acc[c].z * ad_s[cb+2] + acc[c].w * ad_s[cb+3];
  }
  sv += __shfl_xor(sv, 1);
  dv += __shfl_xor(dv, 1);
  if (half == 0){ sarr[node] = sv; darr[node] = dv; }
}

__global__ void k_dense64(const float* __restrict__ x, const float* __restrict__ W,
                          const float* __restrict__ asrc, const float* __restrict__ adst,
                          __half* __restrict__ h16, float* __restrict__ sarr, float* __restrict__ darr,
                          int n){
  __shared__ float4 Ws4[64 * 16];   // 16 KB
  __shared__ float as_s[64], ad_s[64];
  int t = threadIdx.x;
  const float4* W4 = (const float4*)W;
  for (int i = t; i < 64 * 16; i += blockDim.x) Ws4[i] = W4[i];
  if (t < 64){ as_s[t] = asrc[t]; ad_s[t] = adst[t]; }
  __syncthreads();
  int gid = blockIdx.x * blockDim.x + t;
  int node = gid >> 1;
  int half = gid & 1;
  if (node >= n) return;
  const float4* xr = (const float4*)(x + (size_t)node * 64);
  float4 acc[8] = {};
  #pragma unroll
  for (int kk = 0; kk < 16; kk++){
    float4 xv = xr[kk];
    #pragma unroll
    for (int i = 0; i < 4; i++){
      float xk = (i == 0) ? xv.x : (i == 1) ? xv.y : (i == 2) ? xv.z : xv.w;
      const float4* wrow = &Ws4[(kk * 4 + i) * 16 + half * 8];
      #pragma unroll
      for (int c = 0; c < 8; c++){
        acc[c].x = fmaf(xk, wrow[c].x, acc[c].x);
        acc[c].y = fmaf(xk, wrow[c].y, acc[c].y);
        acc[c].z = fmaf(xk, wrow[c].z, acc[c].z);
        acc[c].w = fmaf(xk, wrow[c].w, acc[c].w);
      }
    }
  }
  float sv = 0.f, dv = 0.f;
  #pragma unroll
  for (int c = 0; c < 8; c += 2){
    union { __half2 h2[4]; uint4 u; } pk;
    pk.h2[0] = __floats2half2_rn(acc[c].x,   acc[c].y);
    pk.h2[1] = __floats2half2_rn(acc[c].z,   acc[c].w);
    pk.h2[2] = __floats2half2_rn(acc[c+1].x, acc[c+1].y);
    pk.h2[3] = __floats2half2_rn(acc[c+1].z, acc[c+1].w);
    *(uint4*)(h16 + (size_t)node * 64 + half * 32 + c * 4) = pk.u;
  }
  #pragma unroll
  for (int c = 0; c < 8; c++){
    int cb = half * 32 + c * 4;
    sv += acc[c].x * as_s[cb] + acc[c].y * as_s[cb+1] + acc[c].z * as_s[cb+2] + acc[c].w * as_s[cb+3];
    dv += acc[c].x * ad_s[cb] + acc[c].y * ad_s[cb+1] + acc[c].z * ad_s[cb+2] + acc[c].w * ad_s[cb+3];
  }
  sv += __shfl_xor(sv, 1);
  dv += __shfl_xor(dv, 1);
  if (half == 0){ sarr[node] = sv; darr[node] = dv; }
}

// ---------------- GAT softmax-aggregate (wave per node, fp16 h, LDS stash) ----------------

__device__ __forceinline__ void agg_softmax(const float* sarr, const int* col,
                                            int beg, int deg, float dn, int lane,
                                            int& c0, int& c1, float& a0, float& a1){
  c0 = 0; c1 = 0;
  float e0 = -INFINITY, e1 = -INFINITY;
  if (lane < deg){
    c0 = col[beg + lane];
    float t = sarr[c0] + dn;
    e0 = (t > 0.f) ? t : NEG_SLOPE * t;
  }
  if (lane + 64 < deg){
    c1 = col[beg + lane + 64];
    float t = sarr[c1] + dn;
    e1 = (t > 0.f) ? t : NEG_SLOPE * t;
  }
  float m = wave_reduce_max(fmaxf(e0, e1));
  float w0 = (lane < deg)      ? __expf(e0 - m) : 0.f;
  float w1 = (lane + 64 < deg) ? __expf(e1 - m) : 0.f;
  float sum = wave_reduce_sum(w0 + w1);
  float inv = 1.f / (sum + 1e-16f);
  a0 = w0 * inv; a1 = w1 * inv;
}

__device__ __forceinline__ float4 agg_gather_lds(const __half* h16, int deg, int lane,
                                                 const int2* stash){
  int eg = lane >> 4, cq = lane & 15;
  float4 acc = make_float4(0.f, 0.f, 0.f, 0.f);
  #pragma unroll 2
  for (int j0 = 0; j0 < deg; j0 += 4){
    int idx = j0 + eg;
    if (idx < deg){
      int2 ca = stash[idx];
      float a = __int_as_float(ca.y);
      float2 raw = *(const float2*)(h16 + (size_t)ca.x * 64 + cq * 4);
      __half2 ha = *(__half2*)&raw.x;
      __half2 hb = *(__half2*)&raw.y;
      float2 f0 = __half22float2(ha);
      float2 f1 = __half22float2(hb);
      acc.x = fmaf(a, f0.x, acc.x);
      acc.y = fmaf(a, f0.y, acc.y);
      acc.z = fmaf(a, f1.x, acc.z);
      acc.w = fmaf(a, f1.y, acc.w);
    }
  }
  acc.x += __shfl_xor(acc.x, 16); acc.x += __shfl_xor(acc.x, 32);
  acc.y += __shfl_xor(acc.y, 16); acc.y += __shfl_xor(acc.y, 32);
  acc.z += __shfl_xor(acc.z, 16); acc.z += __shfl_xor(acc.z, 32);
  acc.w += __shfl_xor(acc.w, 16); acc.w += __shfl_xor(acc.w, 32);
  return acc;
}

// layer-1: writes relu(agg + bias) as fp32 [N][64]
__global__ void k_agg1(const __half* __restrict__ h16, const float* __restrict__ sarr,
                       const float* __restrict__ darr, const int* __restrict__ rowptr,
                       const int* __restrict__ col, const float* __restrict__ bias,
                       float* __restrict__ out, int n){
  __shared__ int2 stash[4][128];
  int w = threadIdx.x >> 6;
  int lane = threadIdx.x & 63;
  int node = blockIdx.x * (blockDim.x >> 6) + w;
  bool valid = node < n;
  int beg = 0, deg = 0; float dn = 0.f;
  if (valid){ beg = rowptr[node]; deg = rowptr[node + 1] - beg; dn = darr[node]; }
  bool fast = valid && (deg <= 128);

  if (fast){
    int c0, c1; float a0, a1;
    agg_softmax(sarr, col, beg, deg, dn, lane, c0, c1, a0, a1);
    if (lane < deg)      stash[w][lane]      = make_int2(c0, __float_as_int(a0));
    if (lane + 64 < deg) stash[w][lane + 64] = make_int2(c1, __float_as_int(a1));
  }
  __syncthreads();
  if (fast){
    float4 acc = agg_gather_lds(h16, deg, lane, stash[w]);
    int eg = lane >> 4, cq = lane & 15;
    if (eg == 0){
      const float4 bv = *(const float4*)(bias + cq * 4);
      float4 r;
      r.x = fmaxf(acc.x + bv.x, 0.f);
      r.y = fmaxf(acc.y + bv.y, 0.f);
      r.z = fmaxf(acc.z + bv.z, 0.f);
      r.w = fmaxf(acc.w + bv.w, 0.f);
      *(float4*)(out + (size_t)node * 64 + cq * 4) = r;
    }
  } else if (valid){
    float m = -INFINITY;
    int end = beg + deg;
    for (int j = beg + lane; j < end; j += 64){
      float e = sarr[col[j]] + dn;
      e = (e > 0.f) ? e : NEG_SLOPE * e;
      m = fmaxf(m, e);
    }
    m = wave_reduce_max(m);
    float sum = 0.f;
    for (int j = beg + lane; j < end; j += 64){
      float e = sarr[col[j]] + dn;
      e = (e > 0.f) ? e : NEG_SLOPE * e;
      sum += __expf(e - m);
    }
    sum = wave_reduce_sum(sum);
    float invden = 1.0f / (sum + 1e-16f);
    float acc = 0.f;
    for (int j = beg; j < end; j++){
      int s = col[j];
      float e = sarr[s] + dn;
      e = (e > 0.f) ? e : NEG_SLOPE * e;
      float alpha = __expf(e - m) * invden;
      acc = fmaf(alpha, __half2float(h16[(size_t)s * 64 + lane]), acc);
    }
    float r = acc + bias[lane];
    out[(size_t)node * 64 + lane] = fmaxf(r, 0.f);
  }
}

// layer-2 + fused policy head: writes [N][8] fp32. Wp in registers (8/lane).
__global__ void k_agg2(const __half* __restrict__ h16, const float* __restrict__ sarr,
                       const float* __restrict__ darr, const int* __restrict__ rowptr,
                       const int* __restrict__ col, const float* __restrict__ bias,
                       const float* __restrict__ Wp, const float* __restrict__ bp,
                       float* __restrict__ out, int n){
  __shared__ int2 stash[4][128];
  int w = threadIdx.x >> 6;
  int lane = threadIdx.x & 63;
  int o = lane & 7, g = lane >> 3;
  float wp[8];
  #pragma unroll
  for (int j = 0; j < 8; j++) wp[j] = Wp[(g * 8 + j) * 8 + o];
  float bpv = bp[o];

  int node = blockIdx.x * (blockDim.x >> 6) + w;
  bool valid = node < n;
  int beg = 0, deg = 0; float dn = 0.f;
  if (valid){ beg = rowptr[node]; deg = rowptr[node + 1] - beg; dn = darr[node]; }
  bool fast = valid && (deg <= 128);

  if (fast){
    int c0, c1; float a0, a1;
    agg_softmax(sarr, col, beg, deg, dn, lane, c0, c1, a0, a1);
    if (lane < deg)      stash[w][lane]      = make_int2(c0, __float_as_int(a0));
    if (lane + 64 < deg) stash[w][lane + 64] = make_int2(c1, __float_as_int(a1));
  }
  __syncthreads();
  if (fast){
    float4 acc = agg_gather_lds(h16, deg, lane, stash[w]);
    int cq = lane & 15;
    const float4 bv = *(const float4*)(bias + cq * 4);
    float4 r;
    r.x = fmaxf(acc.x + bv.x, 0.f);
    r.y = fmaxf(acc.y + bv.y, 0.f);
    r.z = fmaxf(acc.z + bv.z, 0.f);
    r.w = fmaxf(acc.w + bv.w, 0.f);
    int s0 = g * 2, s1 = g * 2 + 1;
    float po;
    po  = __shfl(r.x, s0) * wp[0];
    po += __shfl(r.y, s0) * wp[1];
    po += __shfl(r.z, s0) * wp[2];
    po += __shfl(r.w, s0) * wp[3];
    po += __shfl(r.x, s1) * wp[4];
    po += __shfl(r.y, s1) * wp[5];
    po += __shfl(r.z, s1) * wp[6];
    po += __shfl(r.w, s1) * wp[7];
    po += __shfl_xor(po, 8);
    po += __shfl_xor(po, 16);
    po += __shfl_xor(po, 32);
    if (lane < 8) out[(size_t)node * 8 + lane] = po + bpv;
  } else if (valid){
    int end = beg + deg;
    float m = -INFINITY;
    for (int j = beg + lane; j < end; j += 64){
      float e = sarr[col[j]] + dn;
      e = (e > 0.f) ? e : NEG_SLOPE * e;
      m = fmaxf(m, e);
    }
    m = wave_reduce_max(m);
    float sum = 0.f;
    for (int j = beg + lane; j < end; j += 64){
      float e = sarr[col[j]] + dn;
      e = (e > 0.f) ? e : NEG_SLOPE * e;
      sum += __expf(e - m);
    }
    sum = wave_reduce_sum(sum);
    float invden = 1.0f / (sum + 1e-16f);
    float acc = 0.f;
    for (int j = beg; j < end; j++){
      int s = col[j];
      float e = sarr[s] + dn;
      e = (e > 0.f) ? e : NEG_SLOPE * e;
      float alpha = __expf(e - m) * invden;
      acc = fmaf(alpha, __half2float(h16[(size_t)s * 64 + lane]), acc);
    }
    float r = fmaxf(acc + bias[lane], 0.f);
    float po = 0.f;
    #pragma unroll
    for (int j = 0; j < 8; j++) po += __shfl(r, g * 8 + j) * wp[j];
    po += __shfl_xor(po, 8);
    po += __shfl_xor(po, 16);
    po += __shfl_xor(po, 32);
    if (lane < 8) out[(size_t)node * 8 + lane] = po + bpv;
  }
}

// ---------------- launch ----------------

extern "C" void kernel_launch(void* const* d_in, const int* in_sizes, int n_in,
                              void* d_out, int out_size, void* d_ws, size_t ws_size,
                              hipStream_t stream) {
  const float* x   = (const float*)d_in[0];
  const int*   ei  = (const int*)  d_in[1];
  const float* W1  = (const float*)d_in[2];
  const float* as1 = (const float*)d_in[3];
  const float* ad1 = (const float*)d_in[4];
  const float* b1  = (const float*)d_in[5];
  const float* W2  = (const float*)d_in[6];
  const float* as2 = (const float*)d_in[7];
  const float* ad2 = (const float*)d_in[8];
  const float* b2  = (const float*)d_in[9];
  const float* Wp  = (const float*)d_in[10];
  const float* bp  = (const float*)d_in[11];
  float* out = (float*)d_out;

  int N = in_sizes[0] / 16;
  int E = in_sizes[1] / 2;
  int TOT = E + N;
  int NB = (N + 255) >> 8;            // buckets of 256 dst nodes
  int T  = (TOT + TILE - 1) / TILE;   // edge tiles

  char* p = (char*)d_ws;
  auto alloc = [&](size_t bytes) -> char* {
    char* r = p; p += (bytes + 255) & ~(size_t)255; return r;
  };
  __half* h16   = (__half*)alloc((size_t)N * 64 * 2);
  float* buf    = (float*)alloc((size_t)N * 64 * 4);
  float* sA     = (float*)alloc((size_t)N * 4);
  float* dA     = (float*)alloc((size_t)N * 4);
  int*   rowptr = (int*)  alloc((size_t)(N + 1) * 4);
  int*   col    = (int*)  alloc((size_t)TOT * 4);
  int*   Bstart = (int*)  alloc((size_t)(NB + 1) * 4);

  // scratch aliased onto h16/buf (both first written AFTER the CSR build)
  unsigned int* tmp  = (unsigned int*)h16;         // TOT u32 <= N*64*2
  int*          Cmat = (int*)buf;                  // NB*T ints
  int*          Omat = Cmat + (size_t)NB * T;      // NB*T ints

  const int tb = 256;

  // CSR build (dst-grouped) — bucket pipeline only
  k_bcount<<<T, tb, 0, stream>>>(ei, Cmat, E, TOT, NB, T);
  k_bstart<<<1, 512, 0, stream>>>(Cmat, Bstart, rowptr, NB, T, TOT, N);
  k_bcolscan<<<(NB + 3) / 4, tb, 0, stream>>>(Cmat, Bstart, Omat, NB, T);
  k_bscatter<<<T, tb, 0, stream>>>(ei, Omat, tmp, E, TOT, NB, T);
  k_bfinal<<<NB, tb, 0, stream>>>(tmp, Bstart, rowptr, col, N);

  // layer 1
  k_dense16<<<(2 * N + tb - 1) / tb, tb, 0, stream>>>(x, W1, as1, ad1, h16, sA, dA, N);
  k_agg1<<<(N + 3) / 4, 256, 0, stream>>>(h16, sA, dA, rowptr, col, b1, buf, N);
  // layer 2 (+ fused policy head)
  k_dense64<<<(2 * N + tb - 1) / tb, tb, 0, stream>>>(buf, W2, as2, ad2, h16, sA, dA, N);
  k_agg2<<<(N + 3) / 4, 256, 0, stream>>>(h16, sA, dA, rowptr, col, b2, Wp, bp, out, N);
}

// Round 10
// 224.763 us; speedup vs baseline: 3.1035x; 1.0815x over previous
//
#include <hip/hip_runtime.h>
#include <hip/hip_fp16.h>
#include <math.h>

#define NEG_SLOPE 0.2f
#define TILE 8192
// assumes NB = ceil(N/256) <= 512 (N <= 131072)

__device__ __forceinline__ float wave_reduce_sum(float v){
  #pragma unroll
  for (int off = 32; off > 0; off >>= 1) v += __shfl_xor(v, off, 64);
  return v;
}
__device__ __forceinline__ float wave_reduce_max(float v){
  #pragma unroll
  for (int off = 32; off > 0; off >>= 1) v = fmaxf(v, __shfl_xor(v, off, 64));
  return v;
}

// ---------------- CSR build (bucketed) ----------------

// per-tile bucket counts -> C[b][t]; bucket totals -> Btot (atomic)
__global__ void k_bcount(const int* __restrict__ ei, int* __restrict__ C,
                         int* __restrict__ Btot, int E, int TOT, int NB, int T){
  __shared__ int hist[512];
  int t = blockIdx.x;
  for (int i = threadIdx.x; i < NB; i += blockDim.x) hist[i] = 0;
  __syncthreads();
  int base = t * TILE;
  for (int k = threadIdx.x; k < TILE; k += blockDim.x){
    int j = base + k;
    if (j < TOT){
      int d = (j < E) ? ei[E + j] : (j - E);
      atomicAdd(&hist[d >> 8], 1);
    }
  }
  __syncthreads();
  for (int b = threadIdx.x; b < NB; b += blockDim.x){
    int v = hist[b];
    C[(size_t)b * T + t] = v;
    if (v) atomicAdd(&Btot[b], v);
  }
}

// 1 block, 512 threads: exclusive scan of Btot -> Bstart (totals precomputed)
__global__ void k_bstart(const int* __restrict__ Btot, int* __restrict__ Bstart,
                         int* __restrict__ rowptr, int NB, int TOT, int N){
  __shared__ int lds[512];
  int t = threadIdx.x;
  int total = (t < NB) ? Btot[t] : 0;
  lds[t] = total; __syncthreads();
  for (int off = 1; off < 512; off <<= 1){
    int x = (t >= off) ? lds[t - off] : 0;
    __syncthreads();
    lds[t] += x;
    __syncthreads();
  }
  if (t < NB) Bstart[t] = lds[t] - total;   // exclusive
  if (t == 0){ Bstart[NB] = TOT; rowptr[N] = TOT; }
}

__global__ void k_bcolscan(const int* __restrict__ C, const int* __restrict__ Bstart,
                           int* __restrict__ O, int NB, int T){
  int wid = (blockIdx.x * blockDim.x + threadIdx.x) >> 6;
  int lane = threadIdx.x & 63;
  if (wid >= NB) return;
  int run = Bstart[wid];
  int nchunks = (T + 63) / 64;
  for (int i = 0; i < nchunks; i++){
    int t = i * 64 + lane;
    int v = (t < T) ? C[(size_t)wid * T + t] : 0;
    int s = v;
    #pragma unroll
    for (int off = 1; off < 64; off <<= 1){
      int u = __shfl_up(s, off);
      if (lane >= off) s += u;
    }
    if (t < T) O[(size_t)wid * T + t] = run + (s - v);
    run += __shfl(s, 63);
  }
}

__global__ void k_bscatter(const int* __restrict__ ei, const int* __restrict__ O,
                           unsigned int* __restrict__ tmp, int E, int TOT, int NB, int T){
  __shared__ int cur[512];
  int t = blockIdx.x;
  for (int b = threadIdx.x; b < NB; b += blockDim.x) cur[b] = O[(size_t)b * T + t];
  __syncthreads();
  int base = t * TILE;
  for (int k = threadIdx.x; k < TILE; k += blockDim.x){
    int j = base + k;
    if (j < TOT){
      int s, d;
      if (j < E){ s = ei[j]; d = ei[E + j]; } else { s = j - E; d = s; }
      int r = atomicAdd(&cur[d >> 8], 1);
      tmp[r] = ((unsigned)s << 8) | (unsigned)(d & 255);
    }
  }
}

// per bucket: in-LDS degree histogram + scan -> rowptr AND final col scatter
__global__ void k_bfinal(const unsigned int* __restrict__ tmp, const int* __restrict__ Bstart,
                         int* __restrict__ rowptr, int* __restrict__ col, int N){
  __shared__ int hist[256];
  __shared__ int sc[256];
  __shared__ int cur[256];
  int b = blockIdx.x;
  int base_node = b << 8;
  int nnode = min(256, N - base_node);
  int beg = Bstart[b], end = Bstart[b + 1];
  int t = threadIdx.x;
  hist[t] = 0;
  __syncthreads();
  for (int j = beg + t; j < end; j += blockDim.x)
    atomicAdd(&hist[tmp[j] & 255u], 1);
  __syncthreads();
  int v = hist[t];
  sc[t] = v; __syncthreads();
  for (int off = 1; off < 256; off <<= 1){
    int x = (t >= off) ? sc[t - off] : 0;
    __syncthreads();
    sc[t] += x;
    __syncthreads();
  }
  int excl = sc[t] - v;
  if (t < nnode) rowptr[base_node + t] = beg + excl;
  cur[t] = beg + excl;
  __syncthreads();
  for (int j = beg + t; j < end; j += blockDim.x){
    unsigned u = tmp[j];
    int pos = atomicAdd(&cur[u & 255u], 1);
    col[pos] = (int)(u >> 8);
  }
}

// ---------------- dense ops (register-blocked; h output in fp16) ----------------

__global__ void k_dense16(const float* __restrict__ x, const float* __restrict__ W,
                          const float* __restrict__ asrc, const float* __restrict__ adst,
                          __half* __restrict__ h16, float* __restrict__ sarr, float* __restrict__ darr,
                          int n){
  __shared__ float4 Ws4[16 * 16];
  __shared__ float as_s[64], ad_s[64];
  int t = threadIdx.x;
  const float4* W4 = (const float4*)W;
  if (t < 16 * 16) Ws4[t] = W4[t];
  if (t < 64){ as_s[t] = asrc[t]; ad_s[t] = adst[t]; }
  __syncthreads();
  int gid = blockIdx.x * blockDim.x + t;
  int node = gid >> 1;
  int half = gid & 1;
  if (node >= n) return;
  const float4* xr = (const float4*)(x + (size_t)node * 16);
  float4 acc[8] = {};
  #pragma unroll
  for (int kk = 0; kk < 4; kk++){
    float4 xv = xr[kk];
    #pragma unroll
    for (int i = 0; i < 4; i++){
      float xk = (i == 0) ? xv.x : (i == 1) ? xv.y : (i == 2) ? xv.z : xv.w;
      const float4* wrow = &Ws4[(kk * 4 + i) * 16 + half * 8];
      #pragma unroll
      for (int c = 0; c < 8; c++){
        acc[c].x = fmaf(xk, wrow[c].x, acc[c].x);
        acc[c].y = fmaf(xk, wrow[c].y, acc[c].y);
        acc[c].z = fmaf(xk, wrow[c].z, acc[c].z);
        acc[c].w = fmaf(xk, wrow[c].w, acc[c].w);
      }
    }
  }
  float sv = 0.f, dv = 0.f;
  #pragma unroll
  for (int c = 0; c < 8; c += 2){
    union { __half2 h2[4]; uint4 u; } pk;
    pk.h2[0] = __floats2half2_rn(acc[c].x,   acc[c].y);
    pk.h2[1] = __floats2half2_rn(acc[c].z,   acc[c].w);
    pk.h2[2] = __floats2half2_rn(acc[c+1].x, acc[c+1].y);
    pk.h2[3] = __floats2half2_rn(acc[c+1].z, acc[c+1].w);
    *(uint4*)(h16 + (size_t)node * 64 + half * 32 + c * 4) = pk.u;
  }
  #pragma unroll
  for (int c = 0; c < 8; c++){
    int cb = half * 32 + c * 4;
    sv += acc[c].x * as_s[cb] + acc[c].y * as_s[cb+1] + acc[c].z * as_s[cb+2] + acc[c].w * as_s[cb+3];
    dv += acc[c].x * ad_s[cb] + acc[c].y * ad_s[cb+1] + acc[c].z * ad_s[cb+2] + acc[c].w * ad_s[cb+3];
  }
  sv += __shfl_xor(sv, 1);
  dv += __shfl_xor(dv, 1);
  if (half == 0){ sarr[node] = sv; darr[node] = dv; }
}

__global__ void k_dense64(const float* __restrict__ x, const float* __restrict__ W,
                          const float* __restrict__ asrc, const float* __restrict__ adst,
                          __half* __restrict__ h16, float* __restrict__ sarr, float* __restrict__ darr,
                          int n){
  __shared__ float4 Ws4[64 * 16];   // 16 KB
  __shared__ float as_s[64], ad_s[64];
  int t = threadIdx.x;
  const float4* W4 = (const float4*)W;
  for (int i = t; i < 64 * 16; i += blockDim.x) Ws4[i] = W4[i];
  if (t < 64){ as_s[t] = asrc[t]; ad_s[t] = adst[t]; }
  __syncthreads();
  int gid = blockIdx.x * blockDim.x + t;
  int node = gid >> 1;
  int half = gid & 1;
  if (node >= n) return;
  const float4* xr = (const float4*)(x + (size_t)node * 64);
  float4 acc[8] = {};
  #pragma unroll
  for (int kk = 0; kk < 16; kk++){
    float4 xv = xr[kk];
    #pragma unroll
    for (int i = 0; i < 4; i++){
      float xk = (i == 0) ? xv.x : (i == 1) ? xv.y : (i == 2) ? xv.z : xv.w;
      const float4* wrow = &Ws4[(kk * 4 + i) * 16 + half * 8];
      #pragma unroll
      for (int c = 0; c < 8; c++){
        acc[c].x = fmaf(xk, wrow[c].x, acc[c].x);
        acc[c].y = fmaf(xk, wrow[c].y, acc[c].y);
        acc[c].z = fmaf(xk, wrow[c].z, acc[c].z);
        acc[c].w = fmaf(xk, wrow[c].w, acc[c].w);
      }
    }
  }
  float sv = 0.f, dv = 0.f;
  #pragma unroll
  for (int c = 0; c < 8; c += 2){
    union { __half2 h2[4]; uint4 u; } pk;
    pk.h2[0] = __floats2half2_rn(acc[c].x,   acc[c].y);
    pk.h2[1] = __floats2half2_rn(acc[c].z,   acc[c].w);
    pk.h2[2] = __floats2half2_rn(acc[c+1].x, acc[c+1].y);
    pk.h2[3] = __floats2half2_rn(acc[c+1].z, acc[c+1].w);
    *(uint4*)(h16 + (size_t)node * 64 + half * 32 + c * 4) = pk.u;
  }
  #pragma unroll
  for (int c = 0; c < 8; c++){
    int cb = half * 32 + c * 4;
    sv += acc[c].x * as_s[cb] + acc[c].y * as_s[cb+1] + acc[c].z * as_s[cb+2] + acc[c].w * as_s[cb+3];
    dv += acc[c].x * ad_s[cb] + acc[c].y * ad_s[cb+1] + acc[c].z * ad_s[cb+2] + acc[c].w * ad_s[cb+3];
  }
  sv += __shfl_xor(sv, 1);
  dv += __shfl_xor(dv, 1);
  if (half == 0){ sarr[node] = sv; darr[node] = dv; }
}

// ---------------- GAT softmax-aggregate (wave per node, fp16 h, LDS stash) ----------------

__device__ __forceinline__ void agg_softmax(const float* sarr, const int* col,
                                            int beg, int deg, float dn, int lane,
                                            int& c0, int& c1, float& a0, float& a1){
  c0 = 0; c1 = 0;
  float e0 = -INFINITY, e1 = -INFINITY;
  if (lane < deg){
    c0 = col[beg + lane];
    float t = sarr[c0] + dn;
    e0 = (t > 0.f) ? t : NEG_SLOPE * t;
  }
  if (lane + 64 < deg){
    c1 = col[beg + lane + 64];
    float t = sarr[c1] + dn;
    e1 = (t > 0.f) ? t : NEG_SLOPE * t;
  }
  float m = wave_reduce_max(fmaxf(e0, e1));
  float w0 = (lane < deg)      ? __expf(e0 - m) : 0.f;
  float w1 = (lane + 64 < deg) ? __expf(e1 - m) : 0.f;
  float sum = wave_reduce_sum(w0 + w1);
  float inv = 1.f / (sum + 1e-16f);
  a0 = w0 * inv; a1 = w1 * inv;
}

// gather reads (col,alpha) from per-wave LDS stash. Intra-wave ds_write->ds_read
// ordering is handled by compiler lgkmcnt waits; no block barrier needed.
__device__ __forceinline__ float4 agg_gather_lds(const __half* h16, int deg, int lane,
                                                 const int2* stash){
  int eg = lane >> 4, cq = lane & 15;
  float4 acc = make_float4(0.f, 0.f, 0.f, 0.f);
  #pragma unroll 2
  for (int j0 = 0; j0 < deg; j0 += 4){
    int idx = j0 + eg;
    if (idx < deg){
      int2 ca = stash[idx];
      float a = __int_as_float(ca.y);
      float2 raw = *(const float2*)(h16 + (size_t)ca.x * 64 + cq * 4);
      __half2 ha = *(__half2*)&raw.x;
      __half2 hb = *(__half2*)&raw.y;
      float2 f0 = __half22float2(ha);
      float2 f1 = __half22float2(hb);
      acc.x = fmaf(a, f0.x, acc.x);
      acc.y = fmaf(a, f0.y, acc.y);
      acc.z = fmaf(a, f1.x, acc.z);
      acc.w = fmaf(a, f1.y, acc.w);
    }
  }
  acc.x += __shfl_xor(acc.x, 16); acc.x += __shfl_xor(acc.x, 32);
  acc.y += __shfl_xor(acc.y, 16); acc.y += __shfl_xor(acc.y, 32);
  acc.z += __shfl_xor(acc.z, 16); acc.z += __shfl_xor(acc.z, 32);
  acc.w += __shfl_xor(acc.w, 16); acc.w += __shfl_xor(acc.w, 32);
  return acc;
}

// layer-1: writes relu(agg + bias) as fp32 [N][64]
__global__ void k_agg1(const __half* __restrict__ h16, const float* __restrict__ sarr,
                       const float* __restrict__ darr, const int* __restrict__ rowptr,
                       const int* __restrict__ col, const float* __restrict__ bias,
                       float* __restrict__ out, int n){
  __shared__ int2 stash[4][128];
  int w = threadIdx.x >> 6;
  int lane = threadIdx.x & 63;
  int node = blockIdx.x * (blockDim.x >> 6) + w;
  if (node >= n) return;
  int beg = rowptr[node];
  int deg = rowptr[node + 1] - beg;
  float dn = darr[node];

  if (deg <= 128){
    int c0, c1; float a0, a1;
    agg_softmax(sarr, col, beg, deg, dn, lane, c0, c1, a0, a1);
    if (lane < deg)      stash[w][lane]      = make_int2(c0, __float_as_int(a0));
    if (lane + 64 < deg) stash[w][lane + 64] = make_int2(c1, __float_as_int(a1));
    float4 acc = agg_gather_lds(h16, deg, lane, stash[w]);
    int eg = lane >> 4, cq = lane & 15;
    if (eg == 0){
      const float4 bv = *(const float4*)(bias + cq * 4);
      float4 r;
      r.x = fmaxf(acc.x + bv.x, 0.f);
      r.y = fmaxf(acc.y + bv.y, 0.f);
      r.z = fmaxf(acc.z + bv.z, 0.f);
      r.w = fmaxf(acc.w + bv.w, 0.f);
      *(float4*)(out + (size_t)node * 64 + cq * 4) = r;
    }
  } else {
    float m = -INFINITY;
    int end = beg + deg;
    for (int j = beg + lane; j < end; j += 64){
      float e = sarr[col[j]] + dn;
      e = (e > 0.f) ? e : NEG_SLOPE * e;
      m = fmaxf(m, e);
    }
    m = wave_reduce_max(m);
    float sum = 0.f;
    for (int j = beg + lane; j < end; j += 64){
      float e = sarr[col[j]] + dn;
      e = (e > 0.f) ? e : NEG_SLOPE * e;
      sum += __expf(e - m);
    }
    sum = wave_reduce_sum(sum);
    float invden = 1.0f / (sum + 1e-16f);
    float acc = 0.f;
    for (int j = beg; j < end; j++){
      int s = col[j];
      float e = sarr[s] + dn;
      e = (e > 0.f) ? e : NEG_SLOPE * e;
      float alpha = __expf(e - m) * invden;
      acc = fmaf(alpha, __half2float(h16[(size_t)s * 64 + lane]), acc);
    }
    float r = acc + bias[lane];
    out[(size_t)node * 64 + lane] = fmaxf(r, 0.f);
  }
}

// layer-2 + fused policy head: writes [N][8] fp32. Wp in registers (8/lane).
__global__ void k_agg2(const __half* __restrict__ h16, const float* __restrict__ sarr,
                       const float* __restrict__ darr, const int* __restrict__ rowptr,
                       const int* __restrict__ col, const float* __restrict__ bias,
                       const float* __restrict__ Wp, const float* __restrict__ bp,
                       float* __restrict__ out, int n){
  __shared__ int2 stash[4][128];
  int w = threadIdx.x >> 6;
  int lane = threadIdx.x & 63;
  int o = lane & 7, g = lane >> 3;
  float wp[8];
  #pragma unroll
  for (int j = 0; j < 8; j++) wp[j] = Wp[(g * 8 + j) * 8 + o];
  float bpv = bp[o];

  int node = blockIdx.x * (blockDim.x >> 6) + w;
  if (node >= n) return;
  int beg = rowptr[node];
  int deg = rowptr[node + 1] - beg;
  float dn = darr[node];

  if (deg <= 128){
    int c0, c1; float a0, a1;
    agg_softmax(sarr, col, beg, deg, dn, lane, c0, c1, a0, a1);
    if (lane < deg)      stash[w][lane]      = make_int2(c0, __float_as_int(a0));
    if (lane + 64 < deg) stash[w][lane + 64] = make_int2(c1, __float_as_int(a1));
    float4 acc = agg_gather_lds(h16, deg, lane, stash[w]);
    int cq = lane & 15;
    const float4 bv = *(const float4*)(bias + cq * 4);
    float4 r;
    r.x = fmaxf(acc.x + bv.x, 0.f);
    r.y = fmaxf(acc.y + bv.y, 0.f);
    r.z = fmaxf(acc.z + bv.z, 0.f);
    r.w = fmaxf(acc.w + bv.w, 0.f);
    int s0 = g * 2, s1 = g * 2 + 1;
    float po;
    po  = __shfl(r.x, s0) * wp[0];
    po += __shfl(r.y, s0) * wp[1];
    po += __shfl(r.z, s0) * wp[2];
    po += __shfl(r.w, s0) * wp[3];
    po += __shfl(r.x, s1) * wp[4];
    po += __shfl(r.y, s1) * wp[5];
    po += __shfl(r.z, s1) * wp[6];
    po += __shfl(r.w, s1) * wp[7];
    po += __shfl_xor(po, 8);
    po += __shfl_xor(po, 16);
    po += __shfl_xor(po, 32);
    if (lane < 8) out[(size_t)node * 8 + lane] = po + bpv;
  } else {
    int end = beg + deg;
    float m = -INFINITY;
    for (int j = beg + lane; j < end; j += 64){
      float e = sarr[col[j]] + dn;
      e = (e > 0.f) ? e : NEG_SLOPE * e;
      m = fmaxf(m, e);
    }
    m = wave_reduce_max(m);
    float sum = 0.f;
    for (int j = beg + lane; j < end; j += 64){
      float e = sarr[col[j]] + dn;
      e = (e > 0.f) ? e : NEG_SLOPE * e;
      sum += __expf(e - m);
    }
    sum = wave_reduce_sum(sum);
    float invden = 1.0f / (sum + 1e-16f);
    float acc = 0.f;
    for (int j = beg; j < end; j++){
      int s = col[j];
      float e = sarr[s] + dn;
      e = (e > 0.f) ? e : NEG_SLOPE * e;
      float alpha = __expf(e - m) * invden;
      acc = fmaf(alpha, __half2float(h16[(size_t)s * 64 + lane]), acc);
    }
    float r = fmaxf(acc + bias[lane], 0.f);
    float po = 0.f;
    #pragma unroll
    for (int j = 0; j < 8; j++) po += __shfl(r, g * 8 + j) * wp[j];
    po += __shfl_xor(po, 8);
    po += __shfl_xor(po, 16);
    po += __shfl_xor(po, 32);
    if (lane < 8) out[(size_t)node * 8 + lane] = po + bpv;
  }
}

// ---------------- launch ----------------

extern "C" void kernel_launch(void* const* d_in, const int* in_sizes, int n_in,
                              void* d_out, int out_size, void* d_ws, size_t ws_size,
                              hipStream_t stream) {
  const float* x   = (const float*)d_in[0];
  const int*   ei  = (const int*)  d_in[1];
  const float* W1  = (const float*)d_in[2];
  const float* as1 = (const float*)d_in[3];
  const float* ad1 = (const float*)d_in[4];
  const float* b1  = (const float*)d_in[5];
  const float* W2  = (const float*)d_in[6];
  const float* as2 = (const float*)d_in[7];
  const float* ad2 = (const float*)d_in[8];
  const float* b2  = (const float*)d_in[9];
  const float* Wp  = (const float*)d_in[10];
  const float* bp  = (const float*)d_in[11];
  float* out = (float*)d_out;

  int N = in_sizes[0] / 16;
  int E = in_sizes[1] / 2;
  int TOT = E + N;
  int NB = (N + 255) >> 8;            // buckets of 256 dst nodes
  int T  = (TOT + TILE - 1) / TILE;   // edge tiles

  char* p = (char*)d_ws;
  auto alloc = [&](size_t bytes) -> char* {
    char* r = p; p += (bytes + 255) & ~(size_t)255; return r;
  };
  __half* h16   = (__half*)alloc((size_t)N * 64 * 2);
  float* buf    = (float*)alloc((size_t)N * 64 * 4);
  float* sA     = (float*)alloc((size_t)N * 4);
  float* dA     = (float*)alloc((size_t)N * 4);
  int*   rowptr = (int*)  alloc((size_t)(N + 1) * 4);
  int*   col    = (int*)  alloc((size_t)TOT * 4);
  int*   Bstart = (int*)  alloc((size_t)(NB + 1) * 4);
  int*   Btot   = (int*)  alloc((size_t)(NB + 1) * 4);

  // scratch aliased onto h16/buf (both first written AFTER the CSR build)
  unsigned int* tmp  = (unsigned int*)h16;         // TOT u32 <= N*64*2
  int*          Cmat = (int*)buf;                  // NB*T ints
  int*          Omat = Cmat + (size_t)NB * T;      // NB*T ints

  const int tb = 256;

  // CSR build (dst-grouped) — bucket pipeline only
  (void)hipMemsetAsync(Btot, 0, (size_t)(NB + 1) * 4, stream);
  k_bcount<<<T, tb, 0, stream>>>(ei, Cmat, Btot, E, TOT, NB, T);
  k_bstart<<<1, 512, 0, stream>>>(Btot, Bstart, rowptr, NB, TOT, N);
  k_bcolscan<<<(NB + 3) / 4, tb, 0, stream>>>(Cmat, Bstart, Omat, NB, T);
  k_bscatter<<<T, tb, 0, stream>>>(ei, Omat, tmp, E, TOT, NB, T);
  k_bfinal<<<NB, tb, 0, stream>>>(tmp, Bstart, rowptr, col, N);

  // layer 1
  k_dense16<<<(2 * N + tb - 1) / tb, tb, 0, stream>>>(x, W1, as1, ad1, h16, sA, dA, N);
  k_agg1<<<(N + 3) / 4, 256, 0, stream>>>(h16, sA, dA, rowptr, col, b1, buf, N);
  // layer 2 (+ fused policy head)
  k_dense64<<<(2 * N + tb - 1) / tb, tb, 0, stream>>>(buf, W2, as2, ad2, h16, sA, dA, N);
  k_agg2<<<(N + 3) / 4, 256, 0, stream>>>(h16, sA, dA, rowptr, col, b2, Wp, bp, out, N);
}

// Round 11
// 222.450 us; speedup vs baseline: 3.1358x; 1.0104x over previous
//
#include <hip/hip_runtime.h>
#include <hip/hip_fp16.h>
#include <math.h>

#define NEG_SLOPE 0.2f
#define TILE 8192
// assumes NB = ceil(N/256) <= 512 (N <= 131072)

__device__ __forceinline__ float wave_reduce_sum(float v){
  #pragma unroll
  for (int off = 32; off > 0; off >>= 1) v += __shfl_xor(v, off, 64);
  return v;
}
__device__ __forceinline__ float wave_reduce_max(float v){
  #pragma unroll
  for (int off = 32; off > 0; off >>= 1) v = fmaxf(v, __shfl_xor(v, off, 64));
  return v;
}

// ---------------- CSR build (bucketed) ----------------

__global__ void k_bcount(const int* __restrict__ ei, int* __restrict__ C,
                         int* __restrict__ Btot, int E, int TOT, int NB, int T){
  __shared__ int hist[512];
  int t = blockIdx.x;
  for (int i = threadIdx.x; i < NB; i += blockDim.x) hist[i] = 0;
  __syncthreads();
  int base = t * TILE;
  for (int k = threadIdx.x; k < TILE; k += blockDim.x){
    int j = base + k;
    if (j < TOT){
      int d = (j < E) ? ei[E + j] : (j - E);
      atomicAdd(&hist[d >> 8], 1);
    }
  }
  __syncthreads();
  for (int b = threadIdx.x; b < NB; b += blockDim.x){
    int v = hist[b];
    C[(size_t)b * T + t] = v;
    if (v) atomicAdd(&Btot[b], v);
  }
}

__global__ void k_bstart(const int* __restrict__ Btot, int* __restrict__ Bstart,
                         int* __restrict__ rowptr, int NB, int TOT, int N){
  __shared__ int lds[512];
  int t = threadIdx.x;
  int total = (t < NB) ? Btot[t] : 0;
  lds[t] = total; __syncthreads();
  for (int off = 1; off < 512; off <<= 1){
    int x = (t >= off) ? lds[t - off] : 0;
    __syncthreads();
    lds[t] += x;
    __syncthreads();
  }
  if (t < NB) Bstart[t] = lds[t] - total;   // exclusive
  if (t == 0){ Bstart[NB] = TOT; rowptr[N] = TOT; }
}

__global__ void k_bcolscan(const int* __restrict__ C, const int* __restrict__ Bstart,
                           int* __restrict__ O, int NB, int T){
  int wid = (blockIdx.x * blockDim.x + threadIdx.x) >> 6;
  int lane = threadIdx.x & 63;
  if (wid >= NB) return;
  int run = Bstart[wid];
  int nchunks = (T + 63) / 64;
  for (int i = 0; i < nchunks; i++){
    int t = i * 64 + lane;
    int v = (t < T) ? C[(size_t)wid * T + t] : 0;
    int s = v;
    #pragma unroll
    for (int off = 1; off < 64; off <<= 1){
      int u = __shfl_up(s, off);
      if (lane >= off) s += u;
    }
    if (t < T) O[(size_t)wid * T + t] = run + (s - v);
    run += __shfl(s, 63);
  }
}

__global__ void k_bscatter(const int* __restrict__ ei, const int* __restrict__ O,
                           unsigned int* __restrict__ tmp, int E, int TOT, int NB, int T){
  __shared__ int cur[512];
  int t = blockIdx.x;
  for (int b = threadIdx.x; b < NB; b += blockDim.x) cur[b] = O[(size_t)b * T + t];
  __syncthreads();
  int base = t * TILE;
  for (int k = threadIdx.x; k < TILE; k += blockDim.x){
    int j = base + k;
    if (j < TOT){
      int s, d;
      if (j < E){ s = ei[j]; d = ei[E + j]; } else { s = j - E; d = s; }
      int r = atomicAdd(&cur[d >> 8], 1);
      tmp[r] = ((unsigned)s << 8) | (unsigned)(d & 255);
    }
  }
}

__global__ void k_bfinal(const unsigned int* __restrict__ tmp, const int* __restrict__ Bstart,
                         int* __restrict__ rowptr, int* __restrict__ col, int N){
  __shared__ int hist[256];
  __shared__ int sc[256];
  __shared__ int cur[256];
  int b = blockIdx.x;
  int base_node = b << 8;
  int nnode = min(256, N - base_node);
  int beg = Bstart[b], end = Bstart[b + 1];
  int t = threadIdx.x;
  hist[t] = 0;
  __syncthreads();
  for (int j = beg + t; j < end; j += blockDim.x)
    atomicAdd(&hist[tmp[j] & 255u], 1);
  __syncthreads();
  int v = hist[t];
  sc[t] = v; __syncthreads();
  for (int off = 1; off < 256; off <<= 1){
    int x = (t >= off) ? sc[t - off] : 0;
    __syncthreads();
    sc[t] += x;
    __syncthreads();
  }
  int excl = sc[t] - v;
  if (t < nnode) rowptr[base_node + t] = beg + excl;
  cur[t] = beg + excl;
  __syncthreads();
  for (int j = beg + t; j < end; j += blockDim.x){
    unsigned u = tmp[j];
    int pos = atomicAdd(&cur[u & 255u], 1);
    col[pos] = (int)(u >> 8);
  }
}

// ---------------- dense ops (register-blocked; h output in fp16) ----------------

__global__ void k_dense16(const float* __restrict__ x, const float* __restrict__ W,
                          const float* __restrict__ asrc, const float* __restrict__ adst,
                          __half* __restrict__ h16, float* __restrict__ sarr, float* __restrict__ darr,
                          int n){
  __shared__ float4 Ws4[16 * 16];
  __shared__ float as_s[64], ad_s[64];
  int t = threadIdx.x;
  const float4* W4 = (const float4*)W;
  if (t < 16 * 16) Ws4[t] = W4[t];
  if (t < 64){ as_s[t] = asrc[t]; ad_s[t] = adst[t]; }
  __syncthreads();
  int gid = blockIdx.x * blockDim.x + t;
  int node = gid >> 1;
  int half = gid & 1;
  if (node >= n) return;
  const float4* xr = (const float4*)(x + (size_t)node * 16);
  float4 acc[8] = {};
  #pragma unroll
  for (int kk = 0; kk < 4; kk++){
    float4 xv = xr[kk];
    #pragma unroll
    for (int i = 0; i < 4; i++){
      float xk = (i == 0) ? xv.x : (i == 1) ? xv.y : (i == 2) ? xv.z : xv.w;
      const float4* wrow = &Ws4[(kk * 4 + i) * 16 + half * 8];
      #pragma unroll
      for (int c = 0; c < 8; c++){
        acc[c].x = fmaf(xk, wrow[c].x, acc[c].x);
        acc[c].y = fmaf(xk, wrow[c].y, acc[c].y);
        acc[c].z = fmaf(xk, wrow[c].z, acc[c].z);
        acc[c].w = fmaf(xk, wrow[c].w, acc[c].w);
      }
    }
  }
  float sv = 0.f, dv = 0.f;
  #pragma unroll
  for (int c = 0; c < 8; c += 2){
    union { __half2 h2[4]; uint4 u; } pk;
    pk.h2[0] = __floats2half2_rn(acc[c].x,   acc[c].y);
    pk.h2[1] = __floats2half2_rn(acc[c].z,   acc[c].w);
    pk.h2[2] = __floats2half2_rn(acc[c+1].x, acc[c+1].y);
    pk.h2[3] = __floats2half2_rn(acc[c+1].z, acc[c+1].w);
    *(uint4*)(h16 + (size_t)node * 64 + half * 32 + c * 4) = pk.u;
  }
  #pragma unroll
  for (int c = 0; c < 8; c++){
    int cb = half * 32 + c * 4;
    sv += acc[c].x * as_s[cb] + acc[c].y * as_s[cb+1] + acc[c].z * as_s[cb+2] + acc[c].w * as_s[cb+3];
    dv += acc[c].x * ad_s[cb] + acc[c].y * ad_s[cb+1] + acc[c].z * ad_s[cb+2] + acc[c].w * ad_s[cb+3];
  }
  sv += __shfl_xor(sv, 1);
  dv += __shfl_xor(dv, 1);
  if (half == 0){ sarr[node] = sv; darr[node] = dv; }
}

__global__ void k_dense64(const float* __restrict__ x, const float* __restrict__ W,
                          const float* __restrict__ asrc, const float* __restrict__ adst,
                          __half* __restrict__ h16, float* __restrict__ sarr, float* __restrict__ darr,
                          int n){
  __shared__ float4 Ws4[64 * 16];   // 16 KB
  __shared__ float as_s[64], ad_s[64];
  int t = threadIdx.x;
  const float4* W4 = (const float4*)W;
  for (int i = t; i < 64 * 16; i += blockDim.x) Ws4[i] = W4[i];
  if (t < 64){ as_s[t] = asrc[t]; ad_s[t] = adst[t]; }
  __syncthreads();
  int gid = blockIdx.x * blockDim.x + t;
  int node = gid >> 1;
  int half = gid & 1;
  if (node >= n) return;
  const float4* xr = (const float4*)(x + (size_t)node * 64);
  float4 acc[8] = {};
  #pragma unroll
  for (int kk = 0; kk < 16; kk++){
    float4 xv = xr[kk];
    #pragma unroll
    for (int i = 0; i < 4; i++){
      float xk = (i == 0) ? xv.x : (i == 1) ? xv.y : (i == 2) ? xv.z : xv.w;
      const float4* wrow = &Ws4[(kk * 4 + i) * 16 + half * 8];
      #pragma unroll
      for (int c = 0; c < 8; c++){
        acc[c].x = fmaf(xk, wrow[c].x, acc[c].x);
        acc[c].y = fmaf(xk, wrow[c].y, acc[c].y);
        acc[c].z = fmaf(xk, wrow[c].z, acc[c].z);
        acc[c].w = fmaf(xk, wrow[c].w, acc[c].w);
      }
    }
  }
  float sv = 0.f, dv = 0.f;
  #pragma unroll
  for (int c = 0; c < 8; c += 2){
    union { __half2 h2[4]; uint4 u; } pk;
    pk.h2[0] = __floats2half2_rn(acc[c].x,   acc[c].y);
    pk.h2[1] = __floats2half2_rn(acc[c].z,   acc[c].w);
    pk.h2[2] = __floats2half2_rn(acc[c+1].x, acc[c+1].y);
    pk.h2[3] = __floats2half2_rn(acc[c+1].z, acc[c+1].w);
    *(uint4*)(h16 + (size_t)node * 64 + half * 32 + c * 4) = pk.u;
  }
  #pragma unroll
  for (int c = 0; c < 8; c++){
    int cb = half * 32 + c * 4;
    sv += acc[c].x * as_s[cb] + acc[c].y * as_s[cb+1] + acc[c].z * as_s[cb+2] + acc[c].w * as_s[cb+3];
    dv += acc[c].x * ad_s[cb] + acc[c].y * ad_s[cb+1] + acc[c].z * ad_s[cb+2] + acc[c].w * ad_s[cb+3];
  }
  sv += __shfl_xor(sv, 1);
  dv += __shfl_xor(dv, 1);
  if (half == 0){ sarr[node] = sv; darr[node] = dv; }
}

// ---------------- GAT softmax-aggregate (wave per node, fp16 h, LDS stash) ----------------

__device__ __forceinline__ void agg_softmax(const float* sarr, const int* col,
                                            int beg, int deg, float dn, int lane,
                                            int& c0, int& c1, float& a0, float& a1){
  c0 = 0; c1 = 0;
  float e0 = -INFINITY, e1 = -INFINITY;
  if (lane < deg){
    c0 = col[beg + lane];
    float t = sarr[c0] + dn;
    e0 = (t > 0.f) ? t : NEG_SLOPE * t;
  }
  if (lane + 64 < deg){
    c1 = col[beg + lane + 64];
    float t = sarr[c1] + dn;
    e1 = (t > 0.f) ? t : NEG_SLOPE * t;
  }
  float m = wave_reduce_max(fmaxf(e0, e1));
  float w0 = (lane < deg)      ? __expf(e0 - m) : 0.f;
  float w1 = (lane + 64 < deg) ? __expf(e1 - m) : 0.f;
  float sum = wave_reduce_sum(w0 + w1);
  float inv = 1.f / (sum + 1e-16f);
  a0 = w0 * inv; a1 = w1 * inv;
}

// 8 edge-groups (eg = lane&7) x 8 channel-octs (co = lane>>3); 16B loads.
// After the xor-1/2/4 butterfly EVERY lane holds the reduced 8 channels of its oct.
__device__ __forceinline__ void agg_gather16(const __half* h16, int deg, int lane,
                                             const int2* stash, float4& A0, float4& A1){
  int eg = lane & 7, co = lane >> 3;
  float4 a0v = make_float4(0.f,0.f,0.f,0.f), a1v = make_float4(0.f,0.f,0.f,0.f);
  #pragma unroll 2
  for (int j0 = 0; j0 < deg; j0 += 8){
    int idx = j0 + eg;
    if (idx < deg){
      int2 ca = stash[idx];
      float a = __int_as_float(ca.y);
      uint4 raw = *(const uint4*)(h16 + (size_t)ca.x * 64 + co * 8);
      float2 f0 = __half22float2(*(__half2*)&raw.x);
      float2 f1 = __half22float2(*(__half2*)&raw.y);
      float2 f2 = __half22float2(*(__half2*)&raw.z);
      float2 f3 = __half22float2(*(__half2*)&raw.w);
      a0v.x = fmaf(a, f0.x, a0v.x); a0v.y = fmaf(a, f0.y, a0v.y);
      a0v.z = fmaf(a, f1.x, a0v.z); a0v.w = fmaf(a, f1.y, a0v.w);
      a1v.x = fmaf(a, f2.x, a1v.x); a1v.y = fmaf(a, f2.y, a1v.y);
      a1v.z = fmaf(a, f3.x, a1v.z); a1v.w = fmaf(a, f3.y, a1v.w);
    }
  }
  #pragma unroll
  for (int off = 1; off < 8; off <<= 1){
    a0v.x += __shfl_xor(a0v.x, off); a0v.y += __shfl_xor(a0v.y, off);
    a0v.z += __shfl_xor(a0v.z, off); a0v.w += __shfl_xor(a0v.w, off);
    a1v.x += __shfl_xor(a1v.x, off); a1v.y += __shfl_xor(a1v.y, off);
    a1v.z += __shfl_xor(a1v.z, off); a1v.w += __shfl_xor(a1v.w, off);
  }
  A0 = a0v; A1 = a1v;
}

// layer-1: writes relu(agg + bias) as fp32 [N][64]
__global__ void k_agg1(const __half* __restrict__ h16, const float* __restrict__ sarr,
                       const float* __restrict__ darr, const int* __restrict__ rowptr,
                       const int* __restrict__ col, const float* __restrict__ bias,
                       float* __restrict__ out, int n){
  __shared__ int2 stash[4][128];
  int w = threadIdx.x >> 6;
  int lane = threadIdx.x & 63;
  int node = blockIdx.x * (blockDim.x >> 6) + w;
  if (node >= n) return;
  int beg = rowptr[node];
  int deg = rowptr[node + 1] - beg;
  float dn = darr[node];

  if (deg <= 128){
    int c0, c1; float a0, a1;
    agg_softmax(sarr, col, beg, deg, dn, lane, c0, c1, a0, a1);
    if (lane < deg)      stash[w][lane]      = make_int2(c0, __float_as_int(a0));
    if (lane + 64 < deg) stash[w][lane + 64] = make_int2(c1, __float_as_int(a1));
    float4 A0, A1;
    agg_gather16(h16, deg, lane, stash[w], A0, A1);
    int eg = lane & 7, co = lane >> 3;
    if (eg == 0){
      const float4 b0 = *(const float4*)(bias + co * 8);
      const float4 b1 = *(const float4*)(bias + co * 8 + 4);
      float4 r0, r1;
      r0.x = fmaxf(A0.x + b0.x, 0.f); r0.y = fmaxf(A0.y + b0.y, 0.f);
      r0.z = fmaxf(A0.z + b0.z, 0.f); r0.w = fmaxf(A0.w + b0.w, 0.f);
      r1.x = fmaxf(A1.x + b1.x, 0.f); r1.y = fmaxf(A1.y + b1.y, 0.f);
      r1.z = fmaxf(A1.z + b1.z, 0.f); r1.w = fmaxf(A1.w + b1.w, 0.f);
      *(float4*)(out + (size_t)node * 64 + co * 8)     = r0;
      *(float4*)(out + (size_t)node * 64 + co * 8 + 4) = r1;
    }
  } else {
    float m = -INFINITY;
    int end = beg + deg;
    for (int j = beg + lane; j < end; j += 64){
      float e = sarr[col[j]] + dn;
      e = (e > 0.f) ? e : NEG_SLOPE * e;
      m = fmaxf(m, e);
    }
    m = wave_reduce_max(m);
    float sum = 0.f;
    for (int j = beg + lane; j < end; j += 64){
      float e = sarr[col[j]] + dn;
      e = (e > 0.f) ? e : NEG_SLOPE * e;
      sum += __expf(e - m);
    }
    sum = wave_reduce_sum(sum);
    float invden = 1.0f / (sum + 1e-16f);
    float acc = 0.f;
    for (int j = beg; j < end; j++){
      int s = col[j];
      float e = sarr[s] + dn;
      e = (e > 0.f) ? e : NEG_SLOPE * e;
      float alpha = __expf(e - m) * invden;
      acc = fmaf(alpha, __half2float(h16[(size_t)s * 64 + lane]), acc);
    }
    float r = acc + bias[lane];
    out[(size_t)node * 64 + lane] = fmaxf(r, 0.f);
  }
}

// layer-2 + fused policy head: writes [N][8] fp32. Wp slice in registers;
// policy product is IN-LANE (lane (g=co,o=eg) owns channels g*8..g*8+7).
__global__ void k_agg2(const __half* __restrict__ h16, const float* __restrict__ sarr,
                       const float* __restrict__ darr, const int* __restrict__ rowptr,
                       const int* __restrict__ col, const float* __restrict__ bias,
                       const float* __restrict__ Wp, const float* __restrict__ bp,
                       float* __restrict__ out, int n){
  __shared__ int2 stash[4][128];
  int w = threadIdx.x >> 6;
  int lane = threadIdx.x & 63;
  int o = lane & 7, g = lane >> 3;
  float wp[8];
  #pragma unroll
  for (int j = 0; j < 8; j++) wp[j] = Wp[(g * 8 + j) * 8 + o];
  float bpv = bp[o];

  int node = blockIdx.x * (blockDim.x >> 6) + w;
  if (node >= n) return;
  int beg = rowptr[node];
  int deg = rowptr[node + 1] - beg;
  float dn = darr[node];

  if (deg <= 128){
    int c0, c1; float a0, a1;
    agg_softmax(sarr, col, beg, deg, dn, lane, c0, c1, a0, a1);
    if (lane < deg)      stash[w][lane]      = make_int2(c0, __float_as_int(a0));
    if (lane + 64 < deg) stash[w][lane + 64] = make_int2(c1, __float_as_int(a1));
    float4 A0, A1;
    agg_gather16(h16, deg, lane, stash[w], A0, A1);
    // lane holds channels g*8..g*8+7 (g = lane>>3 = co); bias + relu in-lane
    const float4 b0 = *(const float4*)(bias + g * 8);
    const float4 b1 = *(const float4*)(bias + g * 8 + 4);
    float r0 = fmaxf(A0.x + b0.x, 0.f), r1 = fmaxf(A0.y + b0.y, 0.f);
    float r2 = fmaxf(A0.z + b0.z, 0.f), r3 = fmaxf(A0.w + b0.w, 0.f);
    float r4 = fmaxf(A1.x + b1.x, 0.f), r5 = fmaxf(A1.y + b1.y, 0.f);
    float r6 = fmaxf(A1.z + b1.z, 0.f), r7 = fmaxf(A1.w + b1.w, 0.f);
    float po = r0*wp[0] + r1*wp[1] + r2*wp[2] + r3*wp[3]
             + r4*wp[4] + r5*wp[5] + r6*wp[6] + r7*wp[7];
    po += __shfl_xor(po, 8);
    po += __shfl_xor(po, 16);
    po += __shfl_xor(po, 32);
    if (lane < 8) out[(size_t)node * 8 + lane] = po + bpv;
  } else {
    int end = beg + deg;
    float m = -INFINITY;
    for (int j = beg + lane; j < end; j += 64){
      float e = sarr[col[j]] + dn;
      e = (e > 0.f) ? e : NEG_SLOPE * e;
      m = fmaxf(m, e);
    }
    m = wave_reduce_max(m);
    float sum = 0.f;
    for (int j = beg + lane; j < end; j += 64){
      float e = sarr[col[j]] + dn;
      e = (e > 0.f) ? e : NEG_SLOPE * e;
      sum += __expf(e - m);
    }
    sum = wave_reduce_sum(sum);
    float invden = 1.0f / (sum + 1e-16f);
    float acc = 0.f;
    for (int j = beg; j < end; j++){
      int s = col[j];
      float e = sarr[s] + dn;
      e = (e > 0.f) ? e : NEG_SLOPE * e;
      float alpha = __expf(e - m) * invden;
      acc = fmaf(alpha, __half2float(h16[(size_t)s * 64 + lane]), acc);
    }
    float r = fmaxf(acc + bias[lane], 0.f);   // channel = lane
    float po = 0.f;
    #pragma unroll
    for (int j = 0; j < 8; j++) po += __shfl(r, g * 8 + j) * wp[j];
    po += __shfl_xor(po, 8);
    po += __shfl_xor(po, 16);
    po += __shfl_xor(po, 32);
    if (lane < 8) out[(size_t)node * 8 + lane] = po + bpv;
  }
}

// ---------------- launch ----------------

extern "C" void kernel_launch(void* const* d_in, const int* in_sizes, int n_in,
                              void* d_out, int out_size, void* d_ws, size_t ws_size,
                              hipStream_t stream) {
  const float* x   = (const float*)d_in[0];
  const int*   ei  = (const int*)  d_in[1];
  const float* W1  = (const float*)d_in[2];
  const float* as1 = (const float*)d_in[3];
  const float* ad1 = (const float*)d_in[4];
  const float* b1  = (const float*)d_in[5];
  const float* W2  = (const float*)d_in[6];
  const float* as2 = (const float*)d_in[7];
  const float* ad2 = (const float*)d_in[8];
  const float* b2  = (const float*)d_in[9];
  const float* Wp  = (const float*)d_in[10];
  const float* bp  = (const float*)d_in[11];
  float* out = (float*)d_out;

  int N = in_sizes[0] / 16;
  int E = in_sizes[1] / 2;
  int TOT = E + N;
  int NB = (N + 255) >> 8;            // buckets of 256 dst nodes
  int T  = (TOT + TILE - 1) / TILE;   // edge tiles

  char* p = (char*)d_ws;
  auto alloc = [&](size_t bytes) -> char* {
    char* r = p; p += (bytes + 255) & ~(size_t)255; return r;
  };
  __half* h16   = (__half*)alloc((size_t)N * 64 * 2);
  float* buf    = (float*)alloc((size_t)N * 64 * 4);
  float* sA     = (float*)alloc((size_t)N * 4);
  float* dA     = (float*)alloc((size_t)N * 4);
  int*   rowptr = (int*)  alloc((size_t)(N + 1) * 4);
  int*   col    = (int*)  alloc((size_t)TOT * 4);
  int*   Bstart = (int*)  alloc((size_t)(NB + 1) * 4);
  int*   Btot   = (int*)  alloc((size_t)(NB + 1) * 4);

  // scratch aliased onto h16/buf (both first written AFTER the CSR build)
  unsigned int* tmp  = (unsigned int*)h16;         // TOT u32 <= N*64*2
  int*          Cmat = (int*)buf;                  // NB*T ints
  int*          Omat = Cmat + (size_t)NB * T;      // NB*T ints

  const int tb = 256;

  // CSR build (dst-grouped) — bucket pipeline only
  (void)hipMemsetAsync(Btot, 0, (size_t)(NB + 1) * 4, stream);
  k_bcount<<<T, tb, 0, stream>>>(ei, Cmat, Btot, E, TOT, NB, T);
  k_bstart<<<1, 512, 0, stream>>>(Btot, Bstart, rowptr, NB, TOT, N);
  k_bcolscan<<<(NB + 3) / 4, tb, 0, stream>>>(Cmat, Bstart, Omat, NB, T);
  k_bscatter<<<T, tb, 0, stream>>>(ei, Omat, tmp, E, TOT, NB, T);
  k_bfinal<<<NB, tb, 0, stream>>>(tmp, Bstart, rowptr, col, N);

  // layer 1
  k_dense16<<<(2 * N + tb - 1) / tb, tb, 0, stream>>>(x, W1, as1, ad1, h16, sA, dA, N);
  k_agg1<<<(N + 3) / 4, 256, 0, stream>>>(h16, sA, dA, rowptr, col, b1, buf, N);
  // layer 2 (+ fused policy head)
  k_dense64<<<(2 * N + tb - 1) / tb, tb, 0, stream>>>(buf, W2, as2, ad2, h16, sA, dA, N);
  k_agg2<<<(N + 3) / 4, 256, 0, stream>>>(h16, sA, dA, rowptr, col, b2, Wp, bp, out, N);
}